// Round 1
// baseline (3496.733 us; speedup 1.0000x reference)
//
#include <hip/hip_runtime.h>

constexpr int kB = 4, kL = 2048, kD = 1024, kH = 16, kDK = 64;
constexpr int kR = kB * kL; // 8192 rows for the (B*L, D) GEMMs

// ---------------------------------------------------------------------------
// proj_gemm: Y = X @ W^T + bias
//   X: (kR, kD) row-major, W: (kD out, kD in) row-major, bias: (kD)
//   MODE 0: scatter to head layout Y[((b*H + h)*L + i)*DK + d]
//   MODE 1: plain row-major Y[row*kD + col]
// 64x64 tile per 256-thread block, 4x4 micro-tile, K-chunk 16.
// ---------------------------------------------------------------------------
template<int MODE>
__global__ __launch_bounds__(256)
void proj_gemm(const float* __restrict__ X, const float* __restrict__ W,
               const float* __restrict__ bias, float* __restrict__ Y) {
    __shared__ float Xt[16][68];   // [k][row], transposed for b128 reads
    __shared__ float Wt[16][68];   // [k][col]
    const int tid = threadIdx.x;
    const int tx = tid & 15, ty = tid >> 4;
    const int row0 = blockIdx.x * 64;
    const int col0 = blockIdx.y * 64;

    const int rr = tid >> 2;          // 0..63 tile row/col for staging
    const int kq = (tid & 3) * 4;     // k sub-offset (float4)

    float acc[4][4] = {};
    for (int k0 = 0; k0 < kD; k0 += 16) {
        float4 xv = *reinterpret_cast<const float4*>(&X[(size_t)(row0 + rr) * kD + k0 + kq]);
        float4 wv = *reinterpret_cast<const float4*>(&W[(size_t)(col0 + rr) * kD + k0 + kq]);
        __syncthreads();
        Xt[kq + 0][rr] = xv.x; Xt[kq + 1][rr] = xv.y; Xt[kq + 2][rr] = xv.z; Xt[kq + 3][rr] = xv.w;
        Wt[kq + 0][rr] = wv.x; Wt[kq + 1][rr] = wv.y; Wt[kq + 2][rr] = wv.z; Wt[kq + 3][rr] = wv.w;
        __syncthreads();
        #pragma unroll
        for (int kk = 0; kk < 16; ++kk) {
            float4 av = *reinterpret_cast<const float4*>(&Xt[kk][ty * 4]);
            float4 bv = *reinterpret_cast<const float4*>(&Wt[kk][tx * 4]);
            float a[4] = {av.x, av.y, av.z, av.w};
            float b[4] = {bv.x, bv.y, bv.z, bv.w};
            #pragma unroll
            for (int r = 0; r < 4; ++r)
                #pragma unroll
                for (int c = 0; c < 4; ++c)
                    acc[r][c] = fmaf(a[r], b[c], acc[r][c]);
        }
    }
    #pragma unroll
    for (int r = 0; r < 4; ++r) {
        const int row = row0 + ty * 4 + r;
        float4 o;
        o.x = acc[r][0] + bias[col0 + tx * 4 + 0];
        o.y = acc[r][1] + bias[col0 + tx * 4 + 1];
        o.z = acc[r][2] + bias[col0 + tx * 4 + 2];
        o.w = acc[r][3] + bias[col0 + tx * 4 + 3];
        if (MODE == 0) {
            const int bb = row >> 11, i = row & (kL - 1);
            const int h = col0 >> 6;
            *reinterpret_cast<float4*>(
                &Y[(((size_t)bb * kH + h) * kL + i) * kDK + tx * 4]) = o;
        } else {
            *reinterpret_cast<float4*>(&Y[(size_t)row * kD + col0 + tx * 4]) = o;
        }
    }
}

// ---------------------------------------------------------------------------
// Fused flash attention with relative-position bias.
// Block = 256 threads = (16 tx) x (16 ty); handles one (b,h) and 64 Q rows.
// Per 64-col K tile: S = Q K^T + Q W_band^T (fused), online softmax, P V.
// bias[i][j] = sum_d q[i][d] * w_rel[i+j][d]; per micro-tile u = iloc+jloc
// spans 7 consecutive values -> read w[7], fuse fma into the same acc.
// ---------------------------------------------------------------------------
__global__ __launch_bounds__(256)
void attn_fused(const float* __restrict__ qh, const float* __restrict__ kh,
                const float* __restrict__ vh, const float* __restrict__ w_rel,
                float* __restrict__ concat) {
    __shared__ float Qs[64][68];     // [i][d] natural (scalar broadcast reads)
    __shared__ float Kst[64][68];    // [d][j] transposed (b128 b-reads)
    __shared__ float Vs[64][68];     // [j][d] natural (b128 b-reads)
    __shared__ float Wst[64][132];   // [d][u] transposed band, u in [0,127)
    __shared__ float Ps[64][65];     // [i][j] softmax weights
    __shared__ float red[64][17];    // row-reduction scratch
    __shared__ float mrow[64], lrow[64], frow[64];

    const int tid = threadIdx.x;
    const int tx = tid & 15, ty = tid >> 4;
    const int bh = blockIdx.y;              // b*H + h
    const int i0 = blockIdx.x * 64;
    const float* qb = qh + (size_t)bh * kL * kDK;
    const float* kb = kh + (size_t)bh * kL * kDK;
    const float* vb = vh + (size_t)bh * kL * kDK;

    // stage Q tile once (64 x 64)
    #pragma unroll
    for (int m = 0; m < 4; ++m) {
        int idx = tid + m * 256;             // 0..1023
        int r = idx >> 4, dq = (idx & 15) * 4;
        float4 qv = *reinterpret_cast<const float4*>(&qb[(size_t)(i0 + r) * kDK + dq]);
        *reinterpret_cast<float4*>(&Qs[r][dq]) = qv;
    }
    if (tid < 64) { mrow[tid] = -1e30f; lrow[tid] = 0.0f; }

    float oacc[4][4] = {};

    for (int j0 = 0; j0 < kL; j0 += 64) {
        __syncthreads();   // prev-tile PV reads done before overwriting LDS
        #pragma unroll
        for (int m = 0; m < 4; ++m) {
            int idx = tid + m * 256;
            int r = idx >> 4, dq = (idx & 15) * 4;
            float4 kv = *reinterpret_cast<const float4*>(&kb[(size_t)(j0 + r) * kDK + dq]);
            Kst[dq + 0][r] = kv.x; Kst[dq + 1][r] = kv.y;
            Kst[dq + 2][r] = kv.z; Kst[dq + 3][r] = kv.w;
            float4 vv = *reinterpret_cast<const float4*>(&vb[(size_t)(j0 + r) * kDK + dq]);
            *reinterpret_cast<float4*>(&Vs[r][dq]) = vv;
        }
        const int r0 = i0 + j0;   // global w_rel row of u=0 (max r0+126 = 4094)
        #pragma unroll
        for (int m = 0; m < 8; ++m) {
            int idx = tid + m * 256;          // 0..2047
            int r = idx >> 4, dq = (idx & 15) * 4;
            if (r < 127) {
                float4 wv = *reinterpret_cast<const float4*>(&w_rel[(size_t)(r0 + r) * kDK + dq]);
                Wst[dq + 0][r] = wv.x; Wst[dq + 1][r] = wv.y;
                Wst[dq + 2][r] = wv.z; Wst[dq + 3][r] = wv.w;
            }
        }
        __syncthreads();

        // ---- S = (Q K^T + bias) * 0.125 ----
        float acc[4][4] = {};
        const int u0 = (ty + tx) * 4;
        for (int d = 0; d < 64; ++d) {
            float a[4];
            a[0] = Qs[ty * 4 + 0][d]; a[1] = Qs[ty * 4 + 1][d];
            a[2] = Qs[ty * 4 + 2][d]; a[3] = Qs[ty * 4 + 3][d];
            float4 bv = *reinterpret_cast<const float4*>(&Kst[d][tx * 4]);
            float b[4] = {bv.x, bv.y, bv.z, bv.w};
            float w[7];
            #pragma unroll
            for (int u = 0; u < 7; ++u) w[u] = Wst[d][u0 + u];
            #pragma unroll
            for (int r = 0; r < 4; ++r)
                #pragma unroll
                for (int c = 0; c < 4; ++c) {
                    acc[r][c] = fmaf(a[r], b[c], acc[r][c]);
                    acc[r][c] = fmaf(a[r], w[r + c], acc[r][c]);
                }
        }
        #pragma unroll
        for (int r = 0; r < 4; ++r)
            #pragma unroll
            for (int c = 0; c < 4; ++c) acc[r][c] *= 0.125f;

        // ---- online softmax: row max ----
        #pragma unroll
        for (int r = 0; r < 4; ++r) {
            float tm = fmaxf(fmaxf(acc[r][0], acc[r][1]), fmaxf(acc[r][2], acc[r][3]));
            red[ty * 4 + r][tx] = tm;
        }
        __syncthreads();
        if (tid < 64) {
            float tm = red[tid][0];
            #pragma unroll
            for (int q = 1; q < 16; ++q) tm = fmaxf(tm, red[tid][q]);
            float mo = mrow[tid];
            float mn = fmaxf(mo, tm);
            frow[tid] = __expf(mo - mn);
            mrow[tid] = mn;
        }
        __syncthreads();

        // ---- p = exp(s - m), rescale O, partial row sums ----
        #pragma unroll
        for (int r = 0; r < 4; ++r) {
            const float mi = mrow[ty * 4 + r];
            const float fi = frow[ty * 4 + r];
            float s = 0.0f;
            #pragma unroll
            for (int c = 0; c < 4; ++c) {
                float p = __expf(acc[r][c] - mi);
                Ps[ty * 4 + r][tx * 4 + c] = p;
                s += p;
                oacc[r][c] *= fi;
            }
            red[ty * 4 + r][tx] = s;
        }
        __syncthreads();
        if (tid < 64) {
            float s = 0.0f;
            #pragma unroll
            for (int q = 0; q < 16; ++q) s += red[tid][q];
            lrow[tid] = lrow[tid] * frow[tid] + s;
        }

        // ---- O += P V ----
        for (int j = 0; j < 64; ++j) {
            float a[4];
            a[0] = Ps[ty * 4 + 0][j]; a[1] = Ps[ty * 4 + 1][j];
            a[2] = Ps[ty * 4 + 2][j]; a[3] = Ps[ty * 4 + 3][j];
            float4 bv = *reinterpret_cast<const float4*>(&Vs[j][tx * 4]);
            float b[4] = {bv.x, bv.y, bv.z, bv.w};
            #pragma unroll
            for (int r = 0; r < 4; ++r)
                #pragma unroll
                for (int c = 0; c < 4; ++c)
                    oacc[r][c] = fmaf(a[r], b[c], oacc[r][c]);
        }
    }

    __syncthreads();   // lrow final
    const int b = bh >> 4, h = bh & 15;
    #pragma unroll
    for (int r = 0; r < 4; ++r) {
        const int i = i0 + ty * 4 + r;
        const float inv = 1.0f / lrow[ty * 4 + r];
        float4 o;
        o.x = oacc[r][0] * inv; o.y = oacc[r][1] * inv;
        o.z = oacc[r][2] * inv; o.w = oacc[r][3] * inv;
        *reinterpret_cast<float4*>(&concat[((size_t)(b * kL + i)) * kD + h * kDK + tx * 4]) = o;
    }
}

// ---------------------------------------------------------------------------
extern "C" void kernel_launch(void* const* d_in, const int* in_sizes, int n_in,
                              void* d_out, int out_size, void* d_ws, size_t ws_size,
                              hipStream_t stream) {
    const float* q    = (const float*)d_in[0];
    const float* k    = (const float*)d_in[1];
    const float* v    = (const float*)d_in[2];
    const float* Wq   = (const float*)d_in[3];
    const float* bq   = (const float*)d_in[4];
    const float* Wk   = (const float*)d_in[5];
    const float* bk   = (const float*)d_in[6];
    const float* Wv   = (const float*)d_in[7];
    const float* bv   = (const float*)d_in[8];
    const float* Wo   = (const float*)d_in[9];
    const float* bo   = (const float*)d_in[10];
    const float* wrel = (const float*)d_in[11];
    float* out = (float*)d_out;

    // workspace: qh | kh | vh | concat  (4 x 33.55 MB fp32 = 134 MB)
    float* ws = (float*)d_ws;
    const size_t n = (size_t)kB * kL * kD;
    float* qh_w = ws;
    float* kh_w = ws + n;
    float* vh_w = ws + 2 * n;
    float* cc_w = ws + 3 * n;

    dim3 blk(256);
    dim3 gP(kR / 64, kD / 64);
    hipLaunchKernelGGL((proj_gemm<0>), gP, blk, 0, stream, q, Wq, bq, qh_w);
    hipLaunchKernelGGL((proj_gemm<0>), gP, blk, 0, stream, k, Wk, bk, kh_w);
    hipLaunchKernelGGL((proj_gemm<0>), gP, blk, 0, stream, v, Wv, bv, vh_w);

    dim3 gA(kL / 64, kB * kH);
    hipLaunchKernelGGL(attn_fused, gA, blk, 0, stream, qh_w, kh_w, vh_w, wrel, cc_w);

    hipLaunchKernelGGL((proj_gemm<1>), gP, blk, 0, stream, cc_w, Wo, bo, out);
}

// Round 2
// 1044.089 us; speedup vs baseline: 3.3491x; 3.3491x over previous
//
#include <hip/hip_runtime.h>

typedef __attribute__((ext_vector_type(8))) short bf16x8;
typedef __attribute__((ext_vector_type(4))) float f32x4;

constexpr int kB = 4, kL = 2048, kD = 1024, kH = 16, kDK = 64;
constexpr int kR = kB * kL;              // 8192 rows for (B*L, D) GEMMs
constexpr int kWrelMax = 2 * kL - 2;     // 4094 = last valid w_rel row

__device__ inline unsigned short f2bf(float x) {
    union { float f; unsigned u; } v; v.f = x;
    unsigned r = v.u + 0x7FFFu + ((v.u >> 16) & 1u);   // RNE
    return (unsigned short)(r >> 16);
}
__device__ inline float bf2f(unsigned short h) {
    union { unsigned u; float f; } v; v.u = ((unsigned)h) << 16;
    return v.f;
}
__device__ inline void splitf(float x, unsigned short& hi, unsigned short& lo) {
    hi = f2bf(x);
    lo = f2bf(x - bf2f(hi));
}
__device__ inline f32x4 MFMA(bf16x8 a, bf16x8 b, f32x4 c) {
    return __builtin_amdgcn_mfma_f32_16x16x32_bf16(a, b, c, 0, 0, 0);
}

// ---------------------------------------------------------------------------
// K1: fp32 -> bf16 hi/lo split (elementwise, float4)
// ---------------------------------------------------------------------------
__global__ void split4_kernel(const float* __restrict__ in,
                              unsigned short* __restrict__ hi,
                              unsigned short* __restrict__ lo, int n4) {
    int idx = blockIdx.x * blockDim.x + threadIdx.x;
    if (idx >= n4) return;
    float4 x = reinterpret_cast<const float4*>(in)[idx];
    ushort4 h, l;
    splitf(x.x, h.x, l.x); splitf(x.y, h.y, l.y);
    splitf(x.z, h.z, l.z); splitf(x.w, h.w, l.w);
    reinterpret_cast<ushort4*>(hi)[idx] = h;
    reinterpret_cast<ushort4*>(lo)[idx] = l;
}

// ---------------------------------------------------------------------------
// K2/K4: MFMA GEMM  Y = (X @ W^T + bias) * scale
//  AMODE 0: A from fp32 global, split on the fly.  AMODE 1: A pre-split bf16.
//  OMODE 0: write bf16 hi/lo scattered to head layout.  OMODE 1: fp32 plain.
//  128x128 tile, BK=32, 4 waves (2x2), 64x64 per wave, XOR-swizzled LDS.
// ---------------------------------------------------------------------------
template<int AMODE, int OMODE>
__global__ __launch_bounds__(256) void mfma_gemm(
    const float* __restrict__ Af32,
    const unsigned short* __restrict__ Agh, const unsigned short* __restrict__ Agl,
    const unsigned short* __restrict__ Bgh, const unsigned short* __restrict__ Bgl,
    const float* __restrict__ bias, float scale,
    float* __restrict__ Yf, unsigned short* __restrict__ Yh,
    unsigned short* __restrict__ Yl)
{
    __shared__ __align__(16) unsigned short Ash[128 * 32], Asl[128 * 32];
    __shared__ __align__(16) unsigned short Bsh[128 * 32], Bsl[128 * 32];

    const int tid = threadIdx.x;
    const int row0 = blockIdx.x * 128, col0 = blockIdx.y * 128;
    const int w = tid >> 6, lane = tid & 63;
    const int s = lane & 15, g = lane >> 4;
    const int wrow = w >> 1, wcol = w & 1;
    const int srow = tid >> 1;          // 0..127 staging row
    const int skq  = (tid & 1) * 16;    // k offset 0/16

    const f32x4 fz = {0.f, 0.f, 0.f, 0.f};
    f32x4 acc[4][4];
    #pragma unroll
    for (int m = 0; m < 4; ++m)
        #pragma unroll
        for (int n = 0; n < 4; ++n) acc[m][n] = fz;

    float4 aR[4];
    bf16x8 aRh[2], aRl[2], bRh[2], bRl[2];

    auto loadA = [&](int k0) {
        if (AMODE == 0) {
            const float* p = &Af32[(size_t)(row0 + srow) * kD + k0 + skq];
            aR[0] = *(const float4*)(p);
            aR[1] = *(const float4*)(p + 4);
            aR[2] = *(const float4*)(p + 8);
            aR[3] = *(const float4*)(p + 12);
        } else {
            const unsigned short* ph = &Agh[(size_t)(row0 + srow) * kD + k0 + skq];
            const unsigned short* pl = &Agl[(size_t)(row0 + srow) * kD + k0 + skq];
            aRh[0] = *(const bf16x8*)ph; aRh[1] = *(const bf16x8*)(ph + 8);
            aRl[0] = *(const bf16x8*)pl; aRl[1] = *(const bf16x8*)(pl + 8);
        }
    };
    auto loadB = [&](int k0) {
        const unsigned short* ph = &Bgh[(size_t)(col0 + srow) * kD + k0 + skq];
        const unsigned short* pl = &Bgl[(size_t)(col0 + srow) * kD + k0 + skq];
        bRh[0] = *(const bf16x8*)ph; bRh[1] = *(const bf16x8*)(ph + 8);
        bRl[0] = *(const bf16x8*)pl; bRl[1] = *(const bf16x8*)(pl + 8);
    };
    auto writeAB = [&]() {
        const int c0 = skq >> 3, sw = srow & 3;
        bf16x8 h0, h1, l0, l1;
        if (AMODE == 0) {
            const float* af = (const float*)aR;
            #pragma unroll
            for (int q = 0; q < 8; ++q) {
                unsigned short hh, ll;
                splitf(af[q], hh, ll);     h0[q] = (short)hh; l0[q] = (short)ll;
                splitf(af[8 + q], hh, ll); h1[q] = (short)hh; l1[q] = (short)ll;
            }
        } else { h0 = aRh[0]; h1 = aRh[1]; l0 = aRl[0]; l1 = aRl[1]; }
        *(bf16x8*)&Ash[srow * 32 + (((c0    ) ^ sw) << 3)] = h0;
        *(bf16x8*)&Ash[srow * 32 + (((c0 + 1) ^ sw) << 3)] = h1;
        *(bf16x8*)&Asl[srow * 32 + (((c0    ) ^ sw) << 3)] = l0;
        *(bf16x8*)&Asl[srow * 32 + (((c0 + 1) ^ sw) << 3)] = l1;
        *(bf16x8*)&Bsh[srow * 32 + (((c0    ) ^ sw) << 3)] = bRh[0];
        *(bf16x8*)&Bsh[srow * 32 + (((c0 + 1) ^ sw) << 3)] = bRh[1];
        *(bf16x8*)&Bsl[srow * 32 + (((c0    ) ^ sw) << 3)] = bRl[0];
        *(bf16x8*)&Bsl[srow * 32 + (((c0 + 1) ^ sw) << 3)] = bRl[1];
    };

    loadA(0); loadB(0);
    for (int k0 = 0; k0 < kD; k0 += 32) {
        __syncthreads();
        writeAB();
        __syncthreads();
        if (k0 + 32 < kD) { loadA(k0 + 32); loadB(k0 + 32); }

        bf16x8 fAh[4], fAl[4], fBh[4], fBl[4];
        #pragma unroll
        for (int m = 0; m < 4; ++m) {
            int ar = wrow * 64 + m * 16 + s;
            int off = ar * 32 + ((g ^ (ar & 3)) << 3);
            fAh[m] = *(const bf16x8*)&Ash[off];
            fAl[m] = *(const bf16x8*)&Asl[off];
        }
        #pragma unroll
        for (int n = 0; n < 4; ++n) {
            int bc = wcol * 64 + n * 16 + s;
            int off = bc * 32 + ((g ^ (bc & 3)) << 3);
            fBh[n] = *(const bf16x8*)&Bsh[off];
            fBl[n] = *(const bf16x8*)&Bsl[off];
        }
        #pragma unroll
        for (int m = 0; m < 4; ++m)
            #pragma unroll
            for (int n = 0; n < 4; ++n) {
                acc[m][n] = MFMA(fAh[m], fBh[n], acc[m][n]);
                acc[m][n] = MFMA(fAh[m], fBl[n], acc[m][n]);
                acc[m][n] = MFMA(fAl[m], fBh[n], acc[m][n]);
            }
    }

    #pragma unroll
    for (int n = 0; n < 4; ++n) {
        const int colg = col0 + wcol * 64 + n * 16 + s;
        const float bv = bias[colg];
        #pragma unroll
        for (int m = 0; m < 4; ++m) {
            const int rowg = row0 + wrow * 64 + m * 16 + (g << 2);
            #pragma unroll
            for (int r = 0; r < 4; ++r) {
                float val = (acc[m][n][r] + bv) * scale;
                if (OMODE == 0) {
                    const int rg = rowg + r;
                    const int b = rg >> 11, i = rg & (kL - 1);
                    const int h = colg >> 6, d = colg & 63;
                    size_t o = (((size_t)b * kH + h) * kL + i) * kDK + d;
                    unsigned short hh, ll; splitf(val, hh, ll);
                    Yh[o] = hh; Yl[o] = ll;
                } else {
                    Yf[(size_t)(rowg + r) * kD + colg] = val;
                }
            }
        }
    }
}

// ---------------------------------------------------------------------------
// K3: MFMA flash attention with rolling relative-bias GEMM.
// Block = 256 thr = 4 waves (2x2), 64 Q-rows x full j sweep.
// ---------------------------------------------------------------------------
__global__ __launch_bounds__(256) void attn_mfma(
    const unsigned short* __restrict__ Qh, const unsigned short* __restrict__ Ql,
    const unsigned short* __restrict__ Kgh, const unsigned short* __restrict__ Kgl,
    const unsigned short* __restrict__ Vgh, const unsigned short* __restrict__ Vgl,
    const unsigned short* __restrict__ Wr,
    unsigned short* __restrict__ Ch, unsigned short* __restrict__ Cl)
{
    __shared__ __align__(16) unsigned short Kth[64 * 64], Ktl[64 * 64];
    __shared__ __align__(16) unsigned short Vth[64 * 64], Vtl[64 * 64];
    __shared__ __align__(16) unsigned short Wb[64 * 64];
    __shared__ __align__(16) unsigned short Ph[64 * 64], Pl[64 * 64];
    __shared__ __align__(16) unsigned short Tb[64 * 136];
    __shared__ float red[64][2];
    __shared__ float mrow[64], lrow[64], frow[64];

    const int tid = threadIdx.x;
    const int w = tid >> 6, lane = tid & 63;
    const int s = lane & 15, g = lane >> 4;
    const int wrow = w >> 1, wcol = w & 1;
    const int bh = blockIdx.y;
    const int i0 = blockIdx.x * 64;
    const size_t baseQ = (size_t)bh * kL * kDK;

    // --- Q fragments (pre-scaled by 0.125 at projection time) in registers
    bf16x8 qf_h[2][2], qf_l[2][2];
    #pragma unroll
    for (int m = 0; m < 2; ++m)
        #pragma unroll
        for (int ks = 0; ks < 2; ++ks) {
            const int ir = i0 + wrow * 32 + m * 16 + s;
            size_t a = baseQ + (size_t)ir * kDK + ks * 32 + g * 8;
            qf_h[m][ks] = *(const bf16x8*)&Qh[a];
            qf_l[m][ks] = *(const bf16x8*)&Ql[a];
        }

    if (tid < 64) { mrow[tid] = -1e30f; lrow[tid] = 0.f; }

    const f32x4 fz = {0.f, 0.f, 0.f, 0.f};
    f32x4 oacc[2][2];
    #pragma unroll
    for (int m = 0; m < 2; ++m)
        #pragma unroll
        for (int n = 0; n < 2; ++n) oacc[m][n] = fz;

    const int sjr = tid >> 2, sd0 = (tid & 3) * 16;     // row-major staging
    const int svj = tid & 63, svd0 = (tid >> 6) * 16;   // transposed staging

    auto stageRow = [&](const unsigned short* src, long row0, long rmax,
                        unsigned short* dst) {
        long r = row0 + sjr; if (r > rmax) r = rmax;
        const unsigned short* p = &src[r * 64 + sd0];
        bf16x8 v0 = *(const bf16x8*)p;
        bf16x8 v1 = *(const bf16x8*)(p + 8);
        const int c0 = sd0 >> 3, sw = sjr & 7;
        *(bf16x8*)&dst[sjr * 64 + (((c0    ) ^ sw) << 3)] = v0;
        *(bf16x8*)&dst[sjr * 64 + (((c0 + 1) ^ sw) << 3)] = v1;
    };
    auto stageVT = [&](const unsigned short* src, long row0, unsigned short* dst) {
        const unsigned short* p = &src[(row0 + svj) * 64 + svd0];
        bf16x8 v0 = *(const bf16x8*)p;
        bf16x8 v1 = *(const bf16x8*)(p + 8);
        #pragma unroll
        for (int q = 0; q < 8; ++q) {
            int d = svd0 + q;
            dst[d * 64 + (((svj >> 3) ^ (d & 7)) << 3) + (svj & 7)] = (unsigned short)v0[q];
            d = svd0 + 8 + q;
            dst[d * 64 + (((svj >> 3) ^ (d & 7)) << 3) + (svj & 7)] = (unsigned short)v1[q];
        }
    };
    auto tgemmStore = [&](int slotBase) {
        f32x4 tacc[2][2];
        #pragma unroll
        for (int m = 0; m < 2; ++m)
            #pragma unroll
            for (int n = 0; n < 2; ++n) tacc[m][n] = fz;
        bf16x8 wf[2][2];
        #pragma unroll
        for (int n = 0; n < 2; ++n)
            #pragma unroll
            for (int ks = 0; ks < 2; ++ks) {
                const int ur = wcol * 32 + n * 16 + s;
                wf[n][ks] = *(const bf16x8*)&Wb[ur * 64 + (((ks * 4 + g) ^ (ur & 7)) << 3)];
            }
        #pragma unroll
        for (int m = 0; m < 2; ++m)
            #pragma unroll
            for (int n = 0; n < 2; ++n)
                #pragma unroll
                for (int ks = 0; ks < 2; ++ks)
                    tacc[m][n] = MFMA(qf_h[m][ks], wf[n][ks], tacc[m][n]);
        #pragma unroll
        for (int m = 0; m < 2; ++m)
            #pragma unroll
            for (int n = 0; n < 2; ++n)
                #pragma unroll
                for (int r = 0; r < 4; ++r) {
                    const int ir = wrow * 32 + m * 16 + g * 4 + r;
                    const int ul = wcol * 32 + n * 16 + s;
                    Tb[ir * 136 + ((slotBase + ul) & 127)] = f2bf(tacc[m][n][r]);
                }
    };

    // --- prologue: T for u in [0,128)
    stageRow(Wr, i0, kWrelMax, Wb);
    __syncthreads();
    tgemmStore(0);
    __syncthreads();
    stageRow(Wr, i0 + 64, kWrelMax, Wb);
    __syncthreads();
    tgemmStore(64);

    const long baseKV = (long)bh * kL;

    for (int t = 0; t < 32; ++t) {
        const int j0 = t * 64;
        __syncthreads();                        // prev tile fully consumed
        stageRow(Kgh, baseKV + j0, 0x7FFFFFFF, Kth);
        stageRow(Kgl, baseKV + j0, 0x7FFFFFFF, Ktl);
        stageVT(Vgh, baseKV + j0, Vth);
        stageVT(Vgl, baseKV + j0, Vtl);
        if (t >= 1) stageRow(Wr, (long)i0 + 64 + 64 * t, kWrelMax, Wb);
        __syncthreads();
        if (t >= 1) { tgemmStore((64 * (t + 1)) & 127); __syncthreads(); }

        // ---- S = Q K^T (hi/lo x hi/lo, 3 terms) ----
        f32x4 sacc[2][2];
        #pragma unroll
        for (int m = 0; m < 2; ++m)
            #pragma unroll
            for (int n = 0; n < 2; ++n) sacc[m][n] = fz;
        bf16x8 kf_h[2][2], kf_l[2][2];
        #pragma unroll
        for (int n = 0; n < 2; ++n)
            #pragma unroll
            for (int ks = 0; ks < 2; ++ks) {
                const int jc = wcol * 32 + n * 16 + s;
                const int off = jc * 64 + (((ks * 4 + g) ^ (jc & 7)) << 3);
                kf_h[n][ks] = *(const bf16x8*)&Kth[off];
                kf_l[n][ks] = *(const bf16x8*)&Ktl[off];
            }
        #pragma unroll
        for (int m = 0; m < 2; ++m)
            #pragma unroll
            for (int n = 0; n < 2; ++n)
                #pragma unroll
                for (int ks = 0; ks < 2; ++ks) {
                    sacc[m][n] = MFMA(qf_h[m][ks], kf_h[n][ks], sacc[m][n]);
                    sacc[m][n] = MFMA(qf_h[m][ks], kf_l[n][ks], sacc[m][n]);
                    sacc[m][n] = MFMA(qf_l[m][ks], kf_h[n][ks], sacc[m][n]);
                }
        // ---- add gathered relative bias ----
        const int sb = (64 * t) & 127;
        #pragma unroll
        for (int m = 0; m < 2; ++m)
            #pragma unroll
            for (int n = 0; n < 2; ++n)
                #pragma unroll
                for (int r = 0; r < 4; ++r) {
                    const int ir = wrow * 32 + m * 16 + g * 4 + r;
                    const int jc = wcol * 32 + n * 16 + s;
                    sacc[m][n][r] += bf2f(Tb[ir * 136 + ((sb + ir + jc) & 127)]);
                }

        // ---- online softmax: row max ----
        #pragma unroll
        for (int m = 0; m < 2; ++m)
            #pragma unroll
            for (int r = 0; r < 4; ++r) {
                float v = fmaxf(sacc[m][0][r], sacc[m][1][r]);
                v = fmaxf(v, __shfl_xor(v, 1));
                v = fmaxf(v, __shfl_xor(v, 2));
                v = fmaxf(v, __shfl_xor(v, 4));
                v = fmaxf(v, __shfl_xor(v, 8));
                if (s == 0) red[wrow * 32 + m * 16 + g * 4 + r][wcol] = v;
            }
        __syncthreads();
        if (tid < 64) {
            const float tm = fmaxf(red[tid][0], red[tid][1]);
            const float mo = mrow[tid], mn = fmaxf(mo, tm);
            mrow[tid] = mn; frow[tid] = __expf(mo - mn);
        }
        __syncthreads();

        // ---- p = exp(s-m): write P hi/lo, row sums, O rescale ----
        #pragma unroll
        for (int m = 0; m < 2; ++m)
            #pragma unroll
            for (int r = 0; r < 4; ++r) {
                const int ir = wrow * 32 + m * 16 + g * 4 + r;
                const float mi = mrow[ir], fi = frow[ir];
                oacc[m][0][r] *= fi; oacc[m][1][r] *= fi;
                float ls = 0.f;
                #pragma unroll
                for (int n = 0; n < 2; ++n) {
                    const float p = __expf(sacc[m][n][r] - mi);
                    ls += p;
                    unsigned short ph, pl; splitf(p, ph, pl);
                    const int jc = wcol * 32 + n * 16 + s;
                    const int off = ir * 64 + (((jc >> 3) ^ (ir & 7)) << 3) + (jc & 7);
                    Ph[off] = ph; Pl[off] = pl;
                }
                ls += __shfl_xor(ls, 1);
                ls += __shfl_xor(ls, 2);
                ls += __shfl_xor(ls, 4);
                ls += __shfl_xor(ls, 8);
                if (s == 0) red[ir][wcol] = ls;
            }
        __syncthreads();
        if (tid < 64) lrow[tid] = lrow[tid] * frow[tid] + red[tid][0] + red[tid][1];
        __syncthreads();                         // P + Vt ready for PV

        // ---- O += P V ----
        bf16x8 pf_h[2][2], pf_l[2][2], vf_h[2][2], vf_l[2][2];
        #pragma unroll
        for (int m = 0; m < 2; ++m)
            #pragma unroll
            for (int ks = 0; ks < 2; ++ks) {
                const int ir = wrow * 32 + m * 16 + s;
                const int off = ir * 64 + (((ks * 4 + g) ^ (ir & 7)) << 3);
                pf_h[m][ks] = *(const bf16x8*)&Ph[off];
                pf_l[m][ks] = *(const bf16x8*)&Pl[off];
            }
        #pragma unroll
        for (int n = 0; n < 2; ++n)
            #pragma unroll
            for (int ks = 0; ks < 2; ++ks) {
                const int dc = wcol * 32 + n * 16 + s;
                const int off = dc * 64 + (((ks * 4 + g) ^ (dc & 7)) << 3);
                vf_h[n][ks] = *(const bf16x8*)&Vth[off];
                vf_l[n][ks] = *(const bf16x8*)&Vtl[off];
            }
        #pragma unroll
        for (int m = 0; m < 2; ++m)
            #pragma unroll
            for (int n = 0; n < 2; ++n)
                #pragma unroll
                for (int ks = 0; ks < 2; ++ks) {
                    oacc[m][n] = MFMA(pf_h[m][ks], vf_h[n][ks], oacc[m][n]);
                    oacc[m][n] = MFMA(pf_h[m][ks], vf_l[n][ks], oacc[m][n]);
                    oacc[m][n] = MFMA(pf_l[m][ks], vf_h[n][ks], oacc[m][n]);
                }
    }

    // ---- epilogue: O / l -> concat hi/lo ----
    const int b = bh >> 4, h = bh & 15;
    #pragma unroll
    for (int m = 0; m < 2; ++m)
        #pragma unroll
        for (int r = 0; r < 4; ++r) {
            const int ir = wrow * 32 + m * 16 + g * 4 + r;
            const float inv = 1.0f / lrow[ir];
            const int ig = i0 + ir;
            #pragma unroll
            for (int n = 0; n < 2; ++n) {
                const int dc = wcol * 32 + n * 16 + s;
                const float val = oacc[m][n][r] * inv;
                unsigned short hh, ll; splitf(val, hh, ll);
                const size_t o = ((size_t)(b * kL + ig)) * kD + h * kDK + dc;
                Ch[o] = hh; Cl[o] = ll;
            }
        }
}

// ---------------------------------------------------------------------------
extern "C" void kernel_launch(void* const* d_in, const int* in_sizes, int n_in,
                              void* d_out, int out_size, void* d_ws, size_t ws_size,
                              hipStream_t stream) {
    const float* q    = (const float*)d_in[0];
    const float* k    = (const float*)d_in[1];
    const float* v    = (const float*)d_in[2];
    const float* Wq   = (const float*)d_in[3];
    const float* bq   = (const float*)d_in[4];
    const float* Wk   = (const float*)d_in[5];
    const float* bk   = (const float*)d_in[6];
    const float* Wv   = (const float*)d_in[7];
    const float* bv   = (const float*)d_in[8];
    const float* Wo   = (const float*)d_in[9];
    const float* bo   = (const float*)d_in[10];
    const float* wrel = (const float*)d_in[11];
    float* out = (float*)d_out;

    // ---- workspace layout (ushort elements), total ~152 MB ----
    unsigned short* p = (unsigned short*)d_ws;
    const size_t nW = (size_t)kD * kD;          // 1048576
    const size_t nR = (size_t)(2 * kL - 1) * kDK; // 262080
    const size_t nT = (size_t)kB * kL * kD;     // 8388608
    unsigned short* wqh = p; p += nW;  unsigned short* wql = p; p += nW;
    unsigned short* wkh = p; p += nW;  unsigned short* wkl = p; p += nW;
    unsigned short* wvh = p; p += nW;  unsigned short* wvl = p; p += nW;
    unsigned short* woh = p; p += nW;  unsigned short* wol = p; p += nW;
    unsigned short* wrh = p; p += nR;  unsigned short* wrl = p; p += nR;
    unsigned short* qhh = p; p += nT;  unsigned short* qhl = p; p += nT;
    unsigned short* khh = p; p += nT;  unsigned short* khl = p; p += nT;
    unsigned short* vhh = p; p += nT;  unsigned short* vhl = p; p += nT;
    unsigned short* cch = p; p += nT;  unsigned short* ccl = p; p += nT;

    // K1: splits
    hipLaunchKernelGGL(split4_kernel, dim3(1024), dim3(256), 0, stream, Wq, wqh, wql, (int)(nW / 4));
    hipLaunchKernelGGL(split4_kernel, dim3(1024), dim3(256), 0, stream, Wk, wkh, wkl, (int)(nW / 4));
    hipLaunchKernelGGL(split4_kernel, dim3(1024), dim3(256), 0, stream, Wv, wvh, wvl, (int)(nW / 4));
    hipLaunchKernelGGL(split4_kernel, dim3(1024), dim3(256), 0, stream, Wo, woh, wol, (int)(nW / 4));
    hipLaunchKernelGGL(split4_kernel, dim3(256),  dim3(256), 0, stream, wrel, wrh, wrl, (int)(nR / 4));

    // K2: projections (Q pre-scaled by 1/sqrt(dk) = 0.125)
    dim3 blk(256);
    dim3 gP(kR / 128, kD / 128);
    hipLaunchKernelGGL((mfma_gemm<0, 0>), gP, blk, 0, stream,
                       q, nullptr, nullptr, wqh, wql, bq, 0.125f, nullptr, qhh, qhl);
    hipLaunchKernelGGL((mfma_gemm<0, 0>), gP, blk, 0, stream,
                       k, nullptr, nullptr, wkh, wkl, bk, 1.0f, nullptr, khh, khl);
    hipLaunchKernelGGL((mfma_gemm<0, 0>), gP, blk, 0, stream,
                       v, nullptr, nullptr, wvh, wvl, bv, 1.0f, nullptr, vhh, vhl);

    // K3: attention
    dim3 gA(kL / 64, kB * kH);
    hipLaunchKernelGGL(attn_mfma, gA, blk, 0, stream,
                       qhh, qhl, khh, khl, vhh, vhl, wrh, cch, ccl);

    // K4: output projection
    hipLaunchKernelGGL((mfma_gemm<1, 1>), gP, blk, 0, stream,
                       nullptr, cch, ccl, woh, wol, bo, 1.0f, out, nullptr, nullptr);
}

// Round 3
// 669.706 us; speedup vs baseline: 5.2213x; 1.5590x over previous
//
#include <hip/hip_runtime.h>

typedef __attribute__((ext_vector_type(8))) short bf16x8;
typedef __attribute__((ext_vector_type(4))) float f32x4;
typedef unsigned short u16;
typedef unsigned int u32;

constexpr int kB = 4, kL = 2048, kD = 1024, kH = 16, kDK = 64;
constexpr int kR = kB * kL;
constexpr long kWrelMax = 2 * kL - 2;   // 4094 = last valid w_rel row

__device__ inline u16 f2bf(float x) {
    union { float f; u32 u; } v; v.f = x;
    u32 r = v.u + 0x7FFFu + ((v.u >> 16) & 1u);   // RNE
    return (u16)(r >> 16);
}
__device__ inline float bf2f(u16 h) {
    union { u32 u; float f; } v; v.u = ((u32)h) << 16;
    return v.f;
}
__device__ inline void splitf(float x, u16& hi, u16& lo) {
    hi = f2bf(x);
    lo = f2bf(x - bf2f(hi));
}
__device__ inline f32x4 MFMA(bf16x8 a, bf16x8 b, f32x4 c) {
    return __builtin_amdgcn_mfma_f32_16x16x32_bf16(a, b, c, 0, 0, 0);
}
// async global->LDS, 16B per lane; LDS dest = wave-uniform base + lane*16
__device__ __forceinline__ void gll16(const u16* g, u16* l) {
    __builtin_amdgcn_global_load_lds(
        (const __attribute__((address_space(1))) u32*)g,
        (__attribute__((address_space(3))) u32*)l, 16, 0, 0);
}

// ---------------------------------------------------------------------------
// K1: fp32 -> bf16 hi/lo split
// ---------------------------------------------------------------------------
__global__ void split4_kernel(const float* __restrict__ in,
                              u16* __restrict__ hi, u16* __restrict__ lo, int n4) {
    int idx = blockIdx.x * blockDim.x + threadIdx.x;
    if (idx >= n4) return;
    float4 x = reinterpret_cast<const float4*>(in)[idx];
    ushort4 h, l;
    splitf(x.x, h.x, l.x); splitf(x.y, h.y, l.y);
    splitf(x.z, h.z, l.z); splitf(x.w, h.w, l.w);
    reinterpret_cast<ushort4*>(hi)[idx] = h;
    reinterpret_cast<ushort4*>(lo)[idx] = l;
}

// ---------------------------------------------------------------------------
// K2/K4: MFMA GEMM  Y = (X @ W^T + bias) * scale      (unchanged structure)
//  AMODE 0: A fp32 global, split on the fly.  AMODE 1: A pre-split bf16.
//  OMODE 0: head layout hi+lo.  OMODE 1: fp32 plain.  OMODE 2: head hi only.
// ---------------------------------------------------------------------------
template<int AMODE, int OMODE>
__global__ __launch_bounds__(256) void mfma_gemm(
    const float* __restrict__ Af32,
    const u16* __restrict__ Agh, const u16* __restrict__ Agl,
    const u16* __restrict__ Bgh, const u16* __restrict__ Bgl,
    const float* __restrict__ bias, float scale,
    float* __restrict__ Yf, u16* __restrict__ Yh, u16* __restrict__ Yl)
{
    __shared__ __align__(16) u16 Ash[128 * 32], Asl[128 * 32];
    __shared__ __align__(16) u16 Bsh[128 * 32], Bsl[128 * 32];

    const int tid = threadIdx.x;
    const int row0 = blockIdx.x * 128, col0 = blockIdx.y * 128;
    const int w = tid >> 6, lane = tid & 63;
    const int s = lane & 15, g = lane >> 4;
    const int wrow = w >> 1, wcol = w & 1;
    const int srow = tid >> 1;
    const int skq  = (tid & 1) * 16;

    const f32x4 fz = {0.f, 0.f, 0.f, 0.f};
    f32x4 acc[4][4];
    #pragma unroll
    for (int m = 0; m < 4; ++m)
        #pragma unroll
        for (int n = 0; n < 4; ++n) acc[m][n] = fz;

    float4 aR[4];
    bf16x8 aRh[2], aRl[2], bRh[2], bRl[2];

    auto loadA = [&](int k0) {
        if (AMODE == 0) {
            const float* p = &Af32[(size_t)(row0 + srow) * kD + k0 + skq];
            aR[0] = *(const float4*)(p);
            aR[1] = *(const float4*)(p + 4);
            aR[2] = *(const float4*)(p + 8);
            aR[3] = *(const float4*)(p + 12);
        } else {
            const u16* ph = &Agh[(size_t)(row0 + srow) * kD + k0 + skq];
            const u16* pl = &Agl[(size_t)(row0 + srow) * kD + k0 + skq];
            aRh[0] = *(const bf16x8*)ph; aRh[1] = *(const bf16x8*)(ph + 8);
            aRl[0] = *(const bf16x8*)pl; aRl[1] = *(const bf16x8*)(pl + 8);
        }
    };
    auto loadB = [&](int k0) {
        const u16* ph = &Bgh[(size_t)(col0 + srow) * kD + k0 + skq];
        const u16* pl = &Bgl[(size_t)(col0 + srow) * kD + k0 + skq];
        bRh[0] = *(const bf16x8*)ph; bRh[1] = *(const bf16x8*)(ph + 8);
        bRl[0] = *(const bf16x8*)pl; bRl[1] = *(const bf16x8*)(pl + 8);
    };
    auto writeAB = [&]() {
        const int c0 = skq >> 3, sw = srow & 3;
        bf16x8 h0, h1, l0, l1;
        if (AMODE == 0) {
            const float* af = (const float*)aR;
            #pragma unroll
            for (int q = 0; q < 8; ++q) {
                u16 hh, ll;
                splitf(af[q], hh, ll);     h0[q] = (short)hh; l0[q] = (short)ll;
                splitf(af[8 + q], hh, ll); h1[q] = (short)hh; l1[q] = (short)ll;
            }
        } else { h0 = aRh[0]; h1 = aRh[1]; l0 = aRl[0]; l1 = aRl[1]; }
        *(bf16x8*)&Ash[srow * 32 + (((c0    ) ^ sw) << 3)] = h0;
        *(bf16x8*)&Ash[srow * 32 + (((c0 + 1) ^ sw) << 3)] = h1;
        *(bf16x8*)&Asl[srow * 32 + (((c0    ) ^ sw) << 3)] = l0;
        *(bf16x8*)&Asl[srow * 32 + (((c0 + 1) ^ sw) << 3)] = l1;
        *(bf16x8*)&Bsh[srow * 32 + (((c0    ) ^ sw) << 3)] = bRh[0];
        *(bf16x8*)&Bsh[srow * 32 + (((c0 + 1) ^ sw) << 3)] = bRh[1];
        *(bf16x8*)&Bsl[srow * 32 + (((c0    ) ^ sw) << 3)] = bRl[0];
        *(bf16x8*)&Bsl[srow * 32 + (((c0 + 1) ^ sw) << 3)] = bRl[1];
    };

    loadA(0); loadB(0);
    for (int k0 = 0; k0 < kD; k0 += 32) {
        __syncthreads();
        writeAB();
        __syncthreads();
        if (k0 + 32 < kD) { loadA(k0 + 32); loadB(k0 + 32); }

        bf16x8 fAh[4], fAl[4], fBh[4], fBl[4];
        #pragma unroll
        for (int m = 0; m < 4; ++m) {
            int ar = wrow * 64 + m * 16 + s;
            int off = ar * 32 + ((g ^ (ar & 3)) << 3);
            fAh[m] = *(const bf16x8*)&Ash[off];
            fAl[m] = *(const bf16x8*)&Asl[off];
        }
        #pragma unroll
        for (int n = 0; n < 4; ++n) {
            int bc = wcol * 64 + n * 16 + s;
            int off = bc * 32 + ((g ^ (bc & 3)) << 3);
            fBh[n] = *(const bf16x8*)&Bsh[off];
            fBl[n] = *(const bf16x8*)&Bsl[off];
        }
        #pragma unroll
        for (int m = 0; m < 4; ++m)
            #pragma unroll
            for (int n = 0; n < 4; ++n) {
                acc[m][n] = MFMA(fAh[m], fBh[n], acc[m][n]);
                acc[m][n] = MFMA(fAh[m], fBl[n], acc[m][n]);
                acc[m][n] = MFMA(fAl[m], fBh[n], acc[m][n]);
            }
    }

    #pragma unroll
    for (int n = 0; n < 4; ++n) {
        const int colg = col0 + wcol * 64 + n * 16 + s;
        const float bv = bias[colg];
        #pragma unroll
        for (int m = 0; m < 4; ++m) {
            const int rowg = row0 + wrow * 64 + m * 16 + (g << 2);
            #pragma unroll
            for (int r = 0; r < 4; ++r) {
                float val = (acc[m][n][r] + bv) * scale;
                if (OMODE == 1) {
                    Yf[(size_t)(rowg + r) * kD + colg] = val;
                } else {
                    const int rg = rowg + r;
                    const int b = rg >> 11, i = rg & (kL - 1);
                    const int h = colg >> 6, d = colg & 63;
                    size_t o = (((size_t)b * kH + h) * kL + i) * kDK + d;
                    if (OMODE == 0) { u16 hh, ll; splitf(val, hh, ll); Yh[o] = hh; Yl[o] = ll; }
                    else             { Yh[o] = f2bf(val); }
                }
            }
        }
    }
}

// ---------------------------------------------------------------------------
// K3a: 64x64 tile transpose  vh[bh][j][d] -> vT[bh][d][j]
// ---------------------------------------------------------------------------
__global__ __launch_bounds__(256) void transpose64(const u16* __restrict__ src,
                                                   u16* __restrict__ dst) {
    __shared__ u16 tls[64][72];
    const int tid = threadIdx.x;
    const int bh = blockIdx.y, j0 = blockIdx.x * 64;
    const int jr = tid >> 2, d0 = (tid & 3) * 16;
    const u16* p = src + ((size_t)bh * kL + j0 + jr) * kDK + d0;
    *(bf16x8*)&tls[jr][d0]     = *(const bf16x8*)p;
    *(bf16x8*)&tls[jr][d0 + 8] = *(const bf16x8*)(p + 8);
    __syncthreads();
    const int dr = tid >> 2, jc = (tid & 3) * 16;
    __align__(16) u16 tmp[16];
    #pragma unroll
    for (int q = 0; q < 16; ++q) tmp[q] = tls[jc + q][dr];
    u16* pd = dst + ((size_t)bh * kDK + dr) * kL + j0 + jc;
    *(bf16x8*)pd       = *(const bf16x8*)&tmp[0];
    *(bf16x8*)(pd + 8) = *(const bf16x8*)&tmp[8];
}

// ---------------------------------------------------------------------------
// K3: flash attention, 4 waves x 16 rows, j-tile 64, single-bf16 K/V,
//     gll staging (pre-swizzled source), in-wave softmax, 1 barrier/tile.
// ---------------------------------------------------------------------------
__global__ __launch_bounds__(256, 2) void attn3(
    const u16* __restrict__ Qh, const u16* __restrict__ Ql,
    const u16* __restrict__ Kg, const u16* __restrict__ VT,
    const u16* __restrict__ Wr,
    u16* __restrict__ Ch, u16* __restrict__ Cl)
{
    __shared__ __align__(16) u16 Ksh[2][64 * 64];   // [j][d] swizzled
    __shared__ __align__(16) u16 Vsh[2][64 * 64];   // V^T [d][j] swizzled
    __shared__ __align__(16) u16 Wsh[2][64 * 64];   // [u_loc][d] swizzled
    __shared__ __align__(16) u32 Pu[4][16 * 64];    // per-wave P packed hi|lo
    __shared__ __align__(16) u16 Tb[4][16 * 128];   // per-wave bias ring

    const int tid = threadIdx.x;
    const int w = tid >> 6, lane = tid & 63;
    const int s = lane & 15, g = lane >> 4;
    const int bh = blockIdx.y, i0 = blockIdx.x * 64;
    const int b = bh >> 4, h = bh & 15;

    // staging geometry: thread -> dest row (tid>>3)+32*it, dest 16B chunk tid&7
    const int srow = tid >> 3;
    const int sc = tid & 7;

    auto stageK = [&](int buf, int t) {
        const u16* base = Kg + ((size_t)bh * kL + (size_t)t * 64) * kDK;
        #pragma unroll
        for (int it = 0; it < 2; ++it) {
            int r = srow + it * 32;
            gll16(base + r * 64 + ((sc ^ (r & 7)) << 3), &Ksh[buf][it * 2048 + w * 512]);
        }
    };
    auto stageV = [&](int buf, int t) {
        #pragma unroll
        for (int it = 0; it < 2; ++it) {
            int d = srow + it * 32;
            const u16* src = VT + ((size_t)bh * kDK + d) * kL + t * 64 + ((sc ^ (d & 7)) << 3);
            gll16(src, &Vsh[buf][it * 2048 + w * 512]);
        }
    };
    auto stageW = [&](int buf, int c) {
        #pragma unroll
        for (int it = 0; it < 2; ++it) {
            int r = srow + it * 32;
            long row = (long)i0 + 64L * c + r;
            if (row > kWrelMax) row = kWrelMax;
            gll16(Wr + row * 64 + ((sc ^ (r & 7)) << 3), &Wsh[buf][it * 2048 + w * 512]);
        }
    };

    // Q fragments (pre-scaled by 0.125 in projection): row = s, k = ks*32+g*8
    const size_t qbase = ((size_t)bh * kL + i0 + w * 16 + s) * kDK + g * 8;
    bf16x8 qh[2], ql[2];
    qh[0] = *(const bf16x8*)&Qh[qbase];      qh[1] = *(const bf16x8*)&Qh[qbase + 32];
    ql[0] = *(const bf16x8*)&Ql[qbase];      ql[1] = *(const bf16x8*)&Ql[qbase + 32];

    // T-gemm for one 64-u chunk: T[i][u] = Q . Wr^T, store bf16 to ring
    auto computeT = [&](int c, int buf) {
        const f32x4 fz = {0.f, 0.f, 0.f, 0.f};
        f32x4 tacc[4] = {fz, fz, fz, fz};
        #pragma unroll
        for (int un = 0; un < 4; ++un)
            #pragma unroll
            for (int ks = 0; ks < 2; ++ks) {
                int row = un * 16 + s;
                bf16x8 wf = *(const bf16x8*)&Wsh[buf][row * 64 + (((ks * 4 + g) ^ (row & 7)) << 3)];
                tacc[un] = MFMA(qh[ks], wf, tacc[un]);
            }
        const int sbase = (c & 1) * 64;
        #pragma unroll
        for (int un = 0; un < 4; ++un)
            #pragma unroll
            for (int r = 0; r < 4; ++r) {
                int il = g * 4 + r;
                int slot = sbase + un * 16 + s;
                Tb[w][il * 128 + (slot ^ ((il * 2) & 30))] = f2bf(tacc[un][r]);
            }
    };

    // prologue: stage tile 0 + W chunks 0,1; then T chunks 0,1
    stageK(0, 0); stageV(0, 0); stageW(0, 0); stageW(1, 1);
    __syncthreads();
    computeT(0, 0); computeT(1, 1);
    __syncthreads();

    float mS[4] = {-1e30f, -1e30f, -1e30f, -1e30f};
    float lS[4] = {0.f, 0.f, 0.f, 0.f};
    const f32x4 fz = {0.f, 0.f, 0.f, 0.f};
    f32x4 oacc[4] = {fz, fz, fz, fz};

    for (int t = 0; t < 32; ++t) {
        const int cur = t & 1, nxt = cur ^ 1;
        if (t < 31) {                 // async prefetch next tile + W chunk t+2
            stageK(nxt, t + 1);
            stageV(nxt, t + 1);
            stageW(cur, t + 2);
        }
        if (t >= 1) computeT(t + 1, nxt);   // W chunk t+1 staged at t-1

        // ---- S = Q K^T (2 terms) ----
        f32x4 sacc[4] = {fz, fz, fz, fz};
        #pragma unroll
        for (int jn = 0; jn < 4; ++jn)
            #pragma unroll
            for (int ks = 0; ks < 2; ++ks) {
                int row = jn * 16 + s;
                bf16x8 kf = *(const bf16x8*)&Ksh[cur][row * 64 + (((ks * 4 + g) ^ (row & 7)) << 3)];
                sacc[jn] = MFMA(qh[ks], kf, sacc[jn]);
                sacc[jn] = MFMA(ql[ks], kf, sacc[jn]);
            }

        // ---- add relative bias from ring ----
        #pragma unroll
        for (int jn = 0; jn < 4; ++jn)
            #pragma unroll
            for (int r = 0; r < 4; ++r) {
                int il = g * 4 + r;
                int slot = (w * 16 + il + t * 64 + jn * 16 + s) & 127;
                sacc[jn][r] += bf2f(Tb[w][il * 128 + (slot ^ ((il * 2) & 30))]);
            }

        // ---- in-wave online softmax ----
        float f[4];
        #pragma unroll
        for (int r = 0; r < 4; ++r) {
            float tm = fmaxf(fmaxf(sacc[0][r], sacc[1][r]), fmaxf(sacc[2][r], sacc[3][r]));
            tm = fmaxf(tm, __shfl_xor(tm, 1));
            tm = fmaxf(tm, __shfl_xor(tm, 2));
            tm = fmaxf(tm, __shfl_xor(tm, 4));
            tm = fmaxf(tm, __shfl_xor(tm, 8));
            float mo = mS[r], mn = fmaxf(mo, tm);
            mS[r] = mn;
            f[r] = __expf(mo - mn);
            lS[r] *= f[r];
        }
        #pragma unroll
        for (int dn = 0; dn < 4; ++dn)
            #pragma unroll
            for (int r = 0; r < 4; ++r) oacc[dn][r] *= f[r];

        // ---- p = exp(s-m): pack hi|lo u32 -> Pu, accumulate row sums ----
        float psum[4] = {0.f, 0.f, 0.f, 0.f};
        #pragma unroll
        for (int jn = 0; jn < 4; ++jn)
            #pragma unroll
            for (int r = 0; r < 4; ++r) {
                float p = __expf(sacc[jn][r] - mS[r]);
                psum[r] += p;
                u16 ph, pl; splitf(p, ph, pl);
                int il = g * 4 + r;
                int j = jn * 16 + s;
                Pu[w][il * 64 + (((j >> 2) ^ (il & 7)) << 2) + (j & 3)] = ((u32)ph << 16) | pl;
            }
        #pragma unroll
        for (int r = 0; r < 4; ++r) {
            float ps = psum[r];
            ps += __shfl_xor(ps, 1);
            ps += __shfl_xor(ps, 2);
            ps += __shfl_xor(ps, 4);
            ps += __shfl_xor(ps, 8);
            lS[r] += ps;
        }

        // ---- O += P V (2 terms) ----
        #pragma unroll
        for (int ks = 0; ks < 2; ++ks) {
            int c0 = ks * 8 + 2 * g;
            uint4 wa = *(const uint4*)&Pu[w][s * 64 + ((c0 ^ (s & 7)) << 2)];
            uint4 wb = *(const uint4*)&Pu[w][s * 64 + (((c0 | 1) ^ (s & 7)) << 2)];
            bf16x8 ph, pl;
            ph[0] = (short)(wa.x >> 16); pl[0] = (short)(wa.x & 0xffff);
            ph[1] = (short)(wa.y >> 16); pl[1] = (short)(wa.y & 0xffff);
            ph[2] = (short)(wa.z >> 16); pl[2] = (short)(wa.z & 0xffff);
            ph[3] = (short)(wa.w >> 16); pl[3] = (short)(wa.w & 0xffff);
            ph[4] = (short)(wb.x >> 16); pl[4] = (short)(wb.x & 0xffff);
            ph[5] = (short)(wb.y >> 16); pl[5] = (short)(wb.y & 0xffff);
            ph[6] = (short)(wb.z >> 16); pl[6] = (short)(wb.z & 0xffff);
            ph[7] = (short)(wb.w >> 16); pl[7] = (short)(wb.w & 0xffff);
            #pragma unroll
            for (int dn = 0; dn < 4; ++dn) {
                int drow = dn * 16 + s;
                bf16x8 vf = *(const bf16x8*)&Vsh[cur][drow * 64 + (((ks * 4 + g) ^ (drow & 7)) << 3)];
                oacc[dn] = MFMA(ph, vf, oacc[dn]);
                oacc[dn] = MFMA(pl, vf, oacc[dn]);
            }
        }
        __syncthreads();   // drains gll (vmcnt) + releases cur buffers
    }

    // ---- epilogue ----
    float inv[4];
    #pragma unroll
    for (int r = 0; r < 4; ++r) inv[r] = 1.0f / lS[r];
    #pragma unroll
    for (int dn = 0; dn < 4; ++dn)
        #pragma unroll
        for (int r = 0; r < 4; ++r) {
            const int ig = i0 + w * 16 + g * 4 + r;
            float val = oacc[dn][r] * inv[r];
            u16 hh, ll; splitf(val, hh, ll);
            size_t o = ((size_t)(b * kL + ig)) * kD + h * kDK + dn * 16 + s;
            Ch[o] = hh; Cl[o] = ll;
        }
}

// ---------------------------------------------------------------------------
extern "C" void kernel_launch(void* const* d_in, const int* in_sizes, int n_in,
                              void* d_out, int out_size, void* d_ws, size_t ws_size,
                              hipStream_t stream) {
    const float* q    = (const float*)d_in[0];
    const float* k    = (const float*)d_in[1];
    const float* v    = (const float*)d_in[2];
    const float* Wq   = (const float*)d_in[3];
    const float* bq   = (const float*)d_in[4];
    const float* Wk   = (const float*)d_in[5];
    const float* bk   = (const float*)d_in[6];
    const float* Wv   = (const float*)d_in[7];
    const float* bv   = (const float*)d_in[8];
    const float* Wo   = (const float*)d_in[9];
    const float* bo   = (const float*)d_in[10];
    const float* wrel = (const float*)d_in[11];
    float* out = (float*)d_out;

    u16* p = (u16*)d_ws;
    const size_t nW = (size_t)kD * kD;
    const size_t nR = (size_t)(2 * kL - 1) * kDK;
    const size_t nT = (size_t)kB * kL * kD;
    u16* wqh = p; p += nW;  u16* wql = p; p += nW;
    u16* wkh = p; p += nW;  u16* wkl = p; p += nW;
    u16* wvh = p; p += nW;  u16* wvl = p; p += nW;
    u16* woh = p; p += nW;  u16* wol = p; p += nW;
    u16* wrh = p; p += nR;  u16* wrl = p; p += nR;
    u16* qhh = p; p += nT;  u16* qhl = p; p += nT;
    u16* khh = p; p += nT;
    u16* vhh = p; p += nT;
    u16* vT  = p; p += nT;
    u16* cch = p; p += nT;  u16* ccl = p; p += nT;

    hipLaunchKernelGGL(split4_kernel, dim3(1024), dim3(256), 0, stream, Wq, wqh, wql, (int)(nW / 4));
    hipLaunchKernelGGL(split4_kernel, dim3(1024), dim3(256), 0, stream, Wk, wkh, wkl, (int)(nW / 4));
    hipLaunchKernelGGL(split4_kernel, dim3(1024), dim3(256), 0, stream, Wv, wvh, wvl, (int)(nW / 4));
    hipLaunchKernelGGL(split4_kernel, dim3(1024), dim3(256), 0, stream, Wo, woh, wol, (int)(nW / 4));
    hipLaunchKernelGGL(split4_kernel, dim3(256),  dim3(256), 0, stream, wrel, wrh, wrl, (int)(nR / 4));

    dim3 blk(256);
    dim3 gP(kR / 128, kD / 128);
    // Q pre-scaled by 1/sqrt(dk); K,V single-bf16 head layout
    hipLaunchKernelGGL((mfma_gemm<0, 0>), gP, blk, 0, stream,
                       q, nullptr, nullptr, wqh, wql, bq, 0.125f, nullptr, qhh, qhl);
    hipLaunchKernelGGL((mfma_gemm<0, 2>), gP, blk, 0, stream,
                       k, nullptr, nullptr, wkh, wkl, bk, 1.0f, nullptr, khh, nullptr);
    hipLaunchKernelGGL((mfma_gemm<0, 2>), gP, blk, 0, stream,
                       v, nullptr, nullptr, wvh, wvl, bv, 1.0f, nullptr, vhh, nullptr);

    hipLaunchKernelGGL(transpose64, dim3(kL / 64, kB * kH), blk, 0, stream, vhh, vT);

    hipLaunchKernelGGL(attn3, dim3(kL / 64, kB * kH), blk, 0, stream,
                       qhh, qhl, khh, vT, wrh, cch, ccl);

    hipLaunchKernelGGL((mfma_gemm<1, 1>), gP, blk, 0, stream,
                       nullptr, cch, ccl, woh, wol, bo, 1.0f, out, nullptr, nullptr);
}

// Round 5
// 539.147 us; speedup vs baseline: 6.4857x; 1.2422x over previous
//
#include <hip/hip_runtime.h>

typedef __attribute__((ext_vector_type(8))) short bf16x8;
typedef __attribute__((ext_vector_type(4))) float f32x4;
typedef unsigned short u16;
typedef unsigned int u32;

constexpr int kB = 4, kL = 2048, kD = 1024, kH = 16, kDK = 64;
constexpr int kR = kB * kL;
constexpr long kWrelMax = 2 * kL - 2;   // 4094 = last valid w_rel row
constexpr float kQScale = 0.125f * 1.44269504088896f;  // 1/sqrt(dk) * log2(e)

__device__ inline float fexp2(float x) { return __builtin_amdgcn_exp2f(x); }

__device__ inline u16 f2bf(float x) {
    union { float f; u32 u; } v; v.f = x;
    u32 r = v.u + 0x7FFFu + ((v.u >> 16) & 1u);   // RNE
    return (u16)(r >> 16);
}
__device__ inline float bf2f(u16 h) {
    union { u32 u; float f; } v; v.u = ((u32)h) << 16;
    return v.f;
}
__device__ inline void splitf(float x, u16& hi, u16& lo) {
    hi = f2bf(x);
    lo = f2bf(x - bf2f(hi));
}
__device__ inline f32x4 MFMA(bf16x8 a, bf16x8 b, f32x4 c) {
    return __builtin_amdgcn_mfma_f32_16x16x32_bf16(a, b, c, 0, 0, 0);
}
// async global->LDS, 16B per lane; LDS dest = wave-uniform base + lane*16
__device__ __forceinline__ void gll16(const u16* g, u16* l) {
    __builtin_amdgcn_global_load_lds(
        (const __attribute__((address_space(1))) u32*)g,
        (__attribute__((address_space(3))) u32*)l, 16, 0, 0);
}

// ---------------------------------------------------------------------------
// K1: fp32 -> bf16 hi/lo split
// ---------------------------------------------------------------------------
__global__ void split4_kernel(const float* __restrict__ in,
                              u16* __restrict__ hi, u16* __restrict__ lo, int n4) {
    int idx = blockIdx.x * blockDim.x + threadIdx.x;
    if (idx >= n4) return;
    float4 x = reinterpret_cast<const float4*>(in)[idx];
    ushort4 h, l;
    splitf(x.x, h.x, l.x); splitf(x.y, h.y, l.y);
    splitf(x.z, h.z, l.z); splitf(x.w, h.w, l.w);
    reinterpret_cast<ushort4*>(hi)[idx] = h;
    reinterpret_cast<ushort4*>(lo)[idx] = l;
}

// ---------------------------------------------------------------------------
// K2/K4: MFMA GEMM  Y = (X @ W^T + bias) * scale
//  AMODE 0: A fp32 global, split on the fly.  AMODE 1: A pre-split bf16.
//  OMODE 1: fp32 plain.  OMODE 2: head layout, bf16 hi only.  OMODE 0: hi+lo.
//  TERMS 2: Ah*Bh + Al*Bh (exact-A x bf16-B).  TERMS 3: + Ah*Bl.
// ---------------------------------------------------------------------------
template<int AMODE, int OMODE, int TERMS>
__global__ __launch_bounds__(256) void mfma_gemm(
    const float* __restrict__ Af32,
    const u16* __restrict__ Agh, const u16* __restrict__ Agl,
    const u16* __restrict__ Bgh, const u16* __restrict__ Bgl,
    const float* __restrict__ bias, float scale,
    float* __restrict__ Yf, u16* __restrict__ Yh, u16* __restrict__ Yl)
{
    __shared__ __align__(16) u16 Ash[128 * 32], Asl[128 * 32];
    __shared__ __align__(16) u16 Bsh[128 * 32];
    __shared__ __align__(16) u16 Bsl[TERMS == 3 ? 128 * 32 : 8];

    const int tid = threadIdx.x;
    const int row0 = blockIdx.x * 128, col0 = blockIdx.y * 128;
    const int w = tid >> 6, lane = tid & 63;
    const int s = lane & 15, g = lane >> 4;
    const int wrow = w >> 1, wcol = w & 1;
    const int srow = tid >> 1;
    const int skq  = (tid & 1) * 16;

    const f32x4 fz = {0.f, 0.f, 0.f, 0.f};
    f32x4 acc[4][4];
    #pragma unroll
    for (int m = 0; m < 4; ++m)
        #pragma unroll
        for (int n = 0; n < 4; ++n) acc[m][n] = fz;

    float4 aR[4];
    bf16x8 aRh[2], aRl[2], bRh[2], bRl[2];

    auto loadA = [&](int k0) {
        if (AMODE == 0) {
            const float* p = &Af32[(size_t)(row0 + srow) * kD + k0 + skq];
            aR[0] = *(const float4*)(p);
            aR[1] = *(const float4*)(p + 4);
            aR[2] = *(const float4*)(p + 8);
            aR[3] = *(const float4*)(p + 12);
        } else {
            const u16* ph = &Agh[(size_t)(row0 + srow) * kD + k0 + skq];
            const u16* pl = &Agl[(size_t)(row0 + srow) * kD + k0 + skq];
            aRh[0] = *(const bf16x8*)ph; aRh[1] = *(const bf16x8*)(ph + 8);
            aRl[0] = *(const bf16x8*)pl; aRl[1] = *(const bf16x8*)(pl + 8);
        }
    };
    auto loadB = [&](int k0) {
        const u16* ph = &Bgh[(size_t)(col0 + srow) * kD + k0 + skq];
        bRh[0] = *(const bf16x8*)ph; bRh[1] = *(const bf16x8*)(ph + 8);
        if (TERMS == 3) {
            const u16* pl = &Bgl[(size_t)(col0 + srow) * kD + k0 + skq];
            bRl[0] = *(const bf16x8*)pl; bRl[1] = *(const bf16x8*)(pl + 8);
        }
    };
    auto writeAB = [&]() {
        const int c0 = skq >> 3, sw = srow & 3;
        bf16x8 h0, h1, l0, l1;
        if (AMODE == 0) {
            const float* af = (const float*)aR;
            #pragma unroll
            for (int q = 0; q < 8; ++q) {
                u16 hh, ll;
                splitf(af[q], hh, ll);     h0[q] = (short)hh; l0[q] = (short)ll;
                splitf(af[8 + q], hh, ll); h1[q] = (short)hh; l1[q] = (short)ll;
            }
        } else { h0 = aRh[0]; h1 = aRh[1]; l0 = aRl[0]; l1 = aRl[1]; }
        *(bf16x8*)&Ash[srow * 32 + (((c0    ) ^ sw) << 3)] = h0;
        *(bf16x8*)&Ash[srow * 32 + (((c0 + 1) ^ sw) << 3)] = h1;
        *(bf16x8*)&Asl[srow * 32 + (((c0    ) ^ sw) << 3)] = l0;
        *(bf16x8*)&Asl[srow * 32 + (((c0 + 1) ^ sw) << 3)] = l1;
        *(bf16x8*)&Bsh[srow * 32 + (((c0    ) ^ sw) << 3)] = bRh[0];
        *(bf16x8*)&Bsh[srow * 32 + (((c0 + 1) ^ sw) << 3)] = bRh[1];
        if (TERMS == 3) {
            *(bf16x8*)&Bsl[srow * 32 + (((c0    ) ^ sw) << 3)] = bRl[0];
            *(bf16x8*)&Bsl[srow * 32 + (((c0 + 1) ^ sw) << 3)] = bRl[1];
        }
    };

    loadA(0); loadB(0);
    for (int k0 = 0; k0 < kD; k0 += 32) {
        __syncthreads();
        writeAB();
        __syncthreads();
        if (k0 + 32 < kD) { loadA(k0 + 32); loadB(k0 + 32); }

        bf16x8 fAh[4], fAl[4], fBh[4], fBl[4];
        #pragma unroll
        for (int m = 0; m < 4; ++m) {
            int ar = wrow * 64 + m * 16 + s;
            int off = ar * 32 + ((g ^ (ar & 3)) << 3);
            fAh[m] = *(const bf16x8*)&Ash[off];
            fAl[m] = *(const bf16x8*)&Asl[off];
        }
        #pragma unroll
        for (int n = 0; n < 4; ++n) {
            int bc = wcol * 64 + n * 16 + s;
            int off = bc * 32 + ((g ^ (bc & 3)) << 3);
            fBh[n] = *(const bf16x8*)&Bsh[off];
            if (TERMS == 3) fBl[n] = *(const bf16x8*)&Bsl[off];
        }
        #pragma unroll
        for (int m = 0; m < 4; ++m)
            #pragma unroll
            for (int n = 0; n < 4; ++n) {
                acc[m][n] = MFMA(fAh[m], fBh[n], acc[m][n]);
                acc[m][n] = MFMA(fAl[m], fBh[n], acc[m][n]);
                if (TERMS == 3) acc[m][n] = MFMA(fAh[m], fBl[n], acc[m][n]);
            }
    }

    #pragma unroll
    for (int n = 0; n < 4; ++n) {
        const int colg = col0 + wcol * 64 + n * 16 + s;
        const float bv = bias[colg];
        #pragma unroll
        for (int m = 0; m < 4; ++m) {
            const int rowg = row0 + wrow * 64 + m * 16 + (g << 2);
            #pragma unroll
            for (int r = 0; r < 4; ++r) {
                float val = (acc[m][n][r] + bv) * scale;
                if (OMODE == 1) {
                    Yf[(size_t)(rowg + r) * kD + colg] = val;
                } else {
                    const int rg = rowg + r;
                    const int b = rg >> 11, i = rg & (kL - 1);
                    const int h = colg >> 6, d = colg & 63;
                    size_t o = (((size_t)b * kH + h) * kL + i) * kDK + d;
                    if (OMODE == 0) { u16 hh, ll; splitf(val, hh, ll); Yh[o] = hh; Yl[o] = ll; }
                    else             { Yh[o] = f2bf(val); }
                }
            }
        }
    }
}

// ---------------------------------------------------------------------------
// K3a: 64x64 tile transpose  vh[bh][j][d] -> vT[bh][d][j]
// ---------------------------------------------------------------------------
__global__ __launch_bounds__(256) void transpose64(const u16* __restrict__ src,
                                                   u16* __restrict__ dst) {
    __shared__ u16 tls[64][72];
    const int tid = threadIdx.x;
    const int bh = blockIdx.y, j0 = blockIdx.x * 64;
    const int jr = tid >> 2, d0 = (tid & 3) * 16;
    const u16* p = src + ((size_t)bh * kL + j0 + jr) * kDK + d0;
    *(bf16x8*)&tls[jr][d0]     = *(const bf16x8*)p;
    *(bf16x8*)&tls[jr][d0 + 8] = *(const bf16x8*)(p + 8);
    __syncthreads();
    const int dr = tid >> 2, jc = (tid & 3) * 16;
    __align__(16) u16 tmp[16];
    #pragma unroll
    for (int q = 0; q < 16; ++q) tmp[q] = tls[jc + q][dr];
    u16* pd = dst + ((size_t)bh * kDK + dr) * kL + j0 + jc;
    *(bf16x8*)pd       = *(const bf16x8*)&tmp[0];
    *(bf16x8*)(pd + 8) = *(const bf16x8*)&tmp[8];
}

// ---------------------------------------------------------------------------
// K3: flash attention; single-bf16 Q/K/V/P, exp2 domain, gll staging,
//     in-wave softmax, 1 barrier/tile. 4 waves x 16 Q-rows, j-tile 64.
// ---------------------------------------------------------------------------
__global__ __launch_bounds__(256, 2) void attn3(
    const u16* __restrict__ Qh,
    const u16* __restrict__ Kg, const u16* __restrict__ VT,
    const u16* __restrict__ Wr,
    u16* __restrict__ Ch, u16* __restrict__ Cl)
{
    __shared__ __align__(16) u16 Ksh[2][64 * 64];   // [j][d] swizzled
    __shared__ __align__(16) u16 Vsh[2][64 * 64];   // V^T [d][j] swizzled
    __shared__ __align__(16) u16 Wsh[2][64 * 64];   // [u_loc][d] swizzled
    __shared__ __align__(16) u16 Ps[4][16 * 64];    // per-wave P bf16, swizzled
    __shared__ __align__(16) u16 Tb[4][16 * 132];   // per-wave bias ring, stride 132

    const int tid = threadIdx.x;
    const int w = tid >> 6, lane = tid & 63;
    const int s = lane & 15, g = lane >> 4;
    const int bh = blockIdx.y, i0 = blockIdx.x * 64;
    const int b = bh >> 4, h = bh & 15;

    const int srow = tid >> 3;      // staging: dest row (tid>>3)+32*it
    const int sc = tid & 7;         // dest 16B chunk

    auto stageK = [&](int buf, int t) {
        const u16* base = Kg + ((size_t)bh * kL + (size_t)t * 64) * kDK;
        #pragma unroll
        for (int it = 0; it < 2; ++it) {
            int r = srow + it * 32;
            gll16(base + r * 64 + ((sc ^ (r & 7)) << 3), &Ksh[buf][it * 2048 + w * 512]);
        }
    };
    auto stageV = [&](int buf, int t) {
        #pragma unroll
        for (int it = 0; it < 2; ++it) {
            int d = srow + it * 32;
            const u16* src = VT + ((size_t)bh * kDK + d) * kL + t * 64 + ((sc ^ (d & 7)) << 3);
            gll16(src, &Vsh[buf][it * 2048 + w * 512]);
        }
    };
    auto stageW = [&](int buf, int c) {
        #pragma unroll
        for (int it = 0; it < 2; ++it) {
            int r = srow + it * 32;
            long row = (long)i0 + 64L * c + r;
            if (row > kWrelMax) row = kWrelMax;
            gll16(Wr + row * 64 + ((sc ^ (r & 7)) << 3), &Wsh[buf][it * 2048 + w * 512]);
        }
    };

    // Q fragments (pre-scaled by 0.125*log2e in projection)
    const size_t qbase = ((size_t)bh * kL + i0 + w * 16 + s) * kDK + g * 8;
    bf16x8 qh[2];
    qh[0] = *(const bf16x8*)&Qh[qbase];
    qh[1] = *(const bf16x8*)&Qh[qbase + 32];

    // T-gemm (log2-domain bias): T[i][u] = Q . Wr^T -> trunc-bf16 ring store
    auto computeT = [&](int c, int buf) {
        const f32x4 fz = {0.f, 0.f, 0.f, 0.f};
        f32x4 tacc[4] = {fz, fz, fz, fz};
        #pragma unroll
        for (int un = 0; un < 4; ++un)
            #pragma unroll
            for (int ks = 0; ks < 2; ++ks) {
                int row = un * 16 + s;
                bf16x8 wf = *(const bf16x8*)&Wsh[buf][row * 64 + (((ks * 4 + g) ^ (row & 7)) << 3)];
                tacc[un] = MFMA(qh[ks], wf, tacc[un]);
            }
        const int sbase = (c & 1) * 64;
        #pragma unroll
        for (int un = 0; un < 4; ++un)
            #pragma unroll
            for (int r = 0; r < 4; ++r) {
                int il = g * 4 + r;
                Tb[w][il * 132 + sbase + un * 16 + s] =
                    (u16)(__float_as_uint(tacc[un][r]) >> 16);
            }
    };

    // prologue: stage tile 0 + W chunks 0,1; then T chunks 0,1
    stageK(0, 0); stageV(0, 0); stageW(0, 0); stageW(1, 1);
    __syncthreads();
    computeT(0, 0); computeT(1, 1);
    __syncthreads();

    float mS[4] = {-1e30f, -1e30f, -1e30f, -1e30f};
    float lS[4] = {0.f, 0.f, 0.f, 0.f};
    const f32x4 fz = {0.f, 0.f, 0.f, 0.f};
    f32x4 oacc[4] = {fz, fz, fz, fz};

    for (int t = 0; t < 32; ++t) {
        const int cur = t & 1, nxt = cur ^ 1;
        if (t < 31) {                 // async prefetch next tile + W chunk t+2
            stageK(nxt, t + 1);
            stageV(nxt, t + 1);
            stageW(cur, t + 2);
        }
        if (t >= 1) computeT(t + 1, nxt);   // W chunk t+1 staged at t-1

        // ---- S~ = log2e * (QK + bias): QK part (single term) ----
        f32x4 sacc[4] = {fz, fz, fz, fz};
        #pragma unroll
        for (int jn = 0; jn < 4; ++jn)
            #pragma unroll
            for (int ks = 0; ks < 2; ++ks) {
                int row = jn * 16 + s;
                bf16x8 kf = *(const bf16x8*)&Ksh[cur][row * 64 + (((ks * 4 + g) ^ (row & 7)) << 3)];
                sacc[jn] = MFMA(qh[ks], kf, sacc[jn]);
            }

        // ---- add relative bias from ring ----
        #pragma unroll
        for (int jn = 0; jn < 4; ++jn)
            #pragma unroll
            for (int r = 0; r < 4; ++r) {
                int il = g * 4 + r;
                int slot = (w * 16 + il + t * 64 + jn * 16 + s) & 127;
                sacc[jn][r] += bf2f(Tb[w][il * 132 + slot]);
            }

        // ---- in-wave online softmax (log2 domain) ----
        float f[4];
        #pragma unroll
        for (int r = 0; r < 4; ++r) {
            float tm = fmaxf(fmaxf(sacc[0][r], sacc[1][r]), fmaxf(sacc[2][r], sacc[3][r]));
            tm = fmaxf(tm, __shfl_xor(tm, 1));
            tm = fmaxf(tm, __shfl_xor(tm, 2));
            tm = fmaxf(tm, __shfl_xor(tm, 4));
            tm = fmaxf(tm, __shfl_xor(tm, 8));
            float mo = mS[r], mn = fmaxf(mo, tm);
            mS[r] = mn;
            f[r] = fexp2(mo - mn);
            lS[r] *= f[r];
        }
        #pragma unroll
        for (int dn = 0; dn < 4; ++dn)
            #pragma unroll
            for (int r = 0; r < 4; ++r) oacc[dn][r] *= f[r];

        // ---- p = exp2(s-m), truncate to bf16; l accumulates truncated p ----
        float psum[4] = {0.f, 0.f, 0.f, 0.f};
        #pragma unroll
        for (int jn = 0; jn < 4; ++jn)
            #pragma unroll
            for (int r = 0; r < 4; ++r) {
                float p = fexp2(sacc[jn][r] - mS[r]);
                u32 pu = __float_as_uint(p) & 0xFFFF0000u;
                psum[r] += __uint_as_float(pu);
                int il = g * 4 + r;
                int j = jn * 16 + s;
                Ps[w][il * 64 + ((((j >> 3) ^ (il & 7))) << 3) + (j & 7)] = (u16)(pu >> 16);
            }
        #pragma unroll
        for (int r = 0; r < 4; ++r) {
            float ps = psum[r];
            ps += __shfl_xor(ps, 1);
            ps += __shfl_xor(ps, 2);
            ps += __shfl_xor(ps, 4);
            ps += __shfl_xor(ps, 8);
            lS[r] += ps;
        }

        // ---- O += P V (single term) ----
        #pragma unroll
        for (int ks = 0; ks < 2; ++ks) {
            bf16x8 pf = *(const bf16x8*)&Ps[w][s * 64 + ((((ks * 4 + g) ^ (s & 7))) << 3)];
            #pragma unroll
            for (int dn = 0; dn < 4; ++dn) {
                int drow = dn * 16 + s;
                bf16x8 vf = *(const bf16x8*)&Vsh[cur][drow * 64 + (((ks * 4 + g) ^ (drow & 7)) << 3)];
                oacc[dn] = MFMA(pf, vf, oacc[dn]);
            }
        }
        __syncthreads();   // drains gll (vmcnt) + releases cur buffers
    }

    // ---- epilogue ----
    float inv[4];
    #pragma unroll
    for (int r = 0; r < 4; ++r) inv[r] = 1.0f / lS[r];
    #pragma unroll
    for (int dn = 0; dn < 4; ++dn)
        #pragma unroll
        for (int r = 0; r < 4; ++r) {
            const int ig = i0 + w * 16 + g * 4 + r;
            float val = oacc[dn][r] * inv[r];
            u16 hh, ll; splitf(val, hh, ll);
            size_t o = ((size_t)(b * kL + ig)) * kD + h * kDK + dn * 16 + s;
            Ch[o] = hh; Cl[o] = ll;
        }
}

// ---------------------------------------------------------------------------
extern "C" void kernel_launch(void* const* d_in, const int* in_sizes, int n_in,
                              void* d_out, int out_size, void* d_ws, size_t ws_size,
                              hipStream_t stream) {
    const float* q    = (const float*)d_in[0];
    const float* k    = (const float*)d_in[1];
    const float* v    = (const float*)d_in[2];
    const float* Wq   = (const float*)d_in[3];
    const float* bq   = (const float*)d_in[4];
    const float* Wk   = (const float*)d_in[5];
    const float* bk   = (const float*)d_in[6];
    const float* Wv   = (const float*)d_in[7];
    const float* bv   = (const float*)d_in[8];
    const float* Wo   = (const float*)d_in[9];
    const float* bo   = (const float*)d_in[10];
    const float* wrel = (const float*)d_in[11];
    float* out = (float*)d_out;

    u16* p = (u16*)d_ws;
    const size_t nW = (size_t)kD * kD;
    const size_t nR = (size_t)(2 * kL - 1) * kDK;
    const size_t nT = (size_t)kB * kL * kD;
    u16* wqh = p; p += nW;  u16* wql = p; p += nW;
    u16* wkh = p; p += nW;  u16* wkl = p; p += nW;
    u16* wvh = p; p += nW;  u16* wvl = p; p += nW;
    u16* woh = p; p += nW;  u16* wol = p; p += nW;
    u16* wrh = p; p += nR;  u16* wrl = p; p += nR;
    u16* qhh = p; p += nT;
    u16* khh = p; p += nT;
    u16* vhh = p; p += nT;
    u16* vT  = p; p += nT;
    u16* cch = p; p += nT;  u16* ccl = p; p += nT;

    hipLaunchKernelGGL(split4_kernel, dim3(1024), dim3(256), 0, stream, Wq, wqh, wql, (int)(nW / 4));
    hipLaunchKernelGGL(split4_kernel, dim3(1024), dim3(256), 0, stream, Wk, wkh, wkl, (int)(nW / 4));
    hipLaunchKernelGGL(split4_kernel, dim3(1024), dim3(256), 0, stream, Wv, wvh, wvl, (int)(nW / 4));
    hipLaunchKernelGGL(split4_kernel, dim3(1024), dim3(256), 0, stream, Wo, woh, wol, (int)(nW / 4));
    hipLaunchKernelGGL(split4_kernel, dim3(256),  dim3(256), 0, stream, wrel, wrh, wrl, (int)(nR / 4));

    dim3 blk(256);
    dim3 gP(kR / 128, kD / 128);
    // Q pre-scaled by (1/sqrt(dk))*log2(e); all head outputs single-bf16.
    hipLaunchKernelGGL((mfma_gemm<0, 2, 2>), gP, blk, 0, stream,
                       q, nullptr, nullptr, wqh, wql, bq, kQScale, nullptr, qhh, nullptr);
    hipLaunchKernelGGL((mfma_gemm<0, 2, 2>), gP, blk, 0, stream,
                       k, nullptr, nullptr, wkh, wkl, bk, 1.0f, nullptr, khh, nullptr);
    hipLaunchKernelGGL((mfma_gemm<0, 2, 2>), gP, blk, 0, stream,
                       v, nullptr, nullptr, wvh, wvl, bv, 1.0f, nullptr, vhh, nullptr);

    hipLaunchKernelGGL(transpose64, dim3(kL / 64, kB * kH), blk, 0, stream, vhh, vT);

    hipLaunchKernelGGL(attn3, dim3(kL / 64, kB * kH), blk, 0, stream,
                       qhh, khh, vT, wrh, cch, ccl);

    hipLaunchKernelGGL((mfma_gemm<1, 1, 3>), gP, blk, 0, stream,
                       nullptr, cch, ccl, woh, wol, bo, 1.0f, out, nullptr, nullptr);
}

// Round 6
// 449.323 us; speedup vs baseline: 7.7822x; 1.1999x over previous
//
#include <hip/hip_runtime.h>

typedef __attribute__((ext_vector_type(8))) short bf16x8;
typedef __attribute__((ext_vector_type(4))) float f32x4;
typedef unsigned short u16;
typedef unsigned int u32;

constexpr int kB = 4, kL = 2048, kD = 1024, kH = 16, kDK = 64;
constexpr int kR = kB * kL;
constexpr long kWrelMax = 2 * kL - 2;   // 4094 = last valid w_rel row
constexpr float kQScale = 0.125f * 1.44269504088896f;  // 1/sqrt(dk) * log2(e)
constexpr float kM = 12.0f;             // static softmax shift (log2 domain)

__device__ inline float fexp2(float x) { return __builtin_amdgcn_exp2f(x); }

__device__ inline u16 f2bf(float x) {
    union { float f; u32 u; } v; v.f = x;
    u32 r = v.u + 0x7FFFu + ((v.u >> 16) & 1u);   // RNE
    return (u16)(r >> 16);
}
__device__ inline float bf2f(u16 h) {
    union { u32 u; float f; } v; v.u = ((u32)h) << 16;
    return v.f;
}
__device__ inline void splitf(float x, u16& hi, u16& lo) {
    hi = f2bf(x);
    lo = f2bf(x - bf2f(hi));
}
__device__ inline f32x4 MFMA(bf16x8 a, bf16x8 b, f32x4 c) {
    return __builtin_amdgcn_mfma_f32_16x16x32_bf16(a, b, c, 0, 0, 0);
}
// async global->LDS, 16B per lane; LDS dest = wave-uniform base + lane*16
__device__ __forceinline__ void gll16(const u16* g, u16* l) {
    __builtin_amdgcn_global_load_lds(
        (const __attribute__((address_space(1))) u32*)g,
        (__attribute__((address_space(3))) u32*)l, 16, 0, 0);
}

// ---------------------------------------------------------------------------
// K1: fp32 -> bf16 hi/lo split
// ---------------------------------------------------------------------------
__global__ void split4_kernel(const float* __restrict__ in,
                              u16* __restrict__ hi, u16* __restrict__ lo, int n4) {
    int idx = blockIdx.x * blockDim.x + threadIdx.x;
    if (idx >= n4) return;
    float4 x = reinterpret_cast<const float4*>(in)[idx];
    ushort4 h, l;
    splitf(x.x, h.x, l.x); splitf(x.y, h.y, l.y);
    splitf(x.z, h.z, l.z); splitf(x.w, h.w, l.w);
    reinterpret_cast<ushort4*>(hi)[idx] = h;
    reinterpret_cast<ushort4*>(lo)[idx] = l;
}

// ---------------------------------------------------------------------------
// K2/K4: MFMA GEMM  Y = (X @ W^T + bias) * scale
//  AMODE 0: A fp32 global, split on the fly.  AMODE 1: A pre-split bf16.
//  OMODE 1: fp32 plain.  OMODE 2: head layout, bf16 hi only.  OMODE 0: hi+lo.
//  TERMS 2: Ah*Bh + Al*Bh (exact-A x bf16-B).  TERMS 3: + Ah*Bl.
// ---------------------------------------------------------------------------
template<int AMODE, int OMODE, int TERMS>
__global__ __launch_bounds__(256) void mfma_gemm(
    const float* __restrict__ Af32,
    const u16* __restrict__ Agh, const u16* __restrict__ Agl,
    const u16* __restrict__ Bgh, const u16* __restrict__ Bgl,
    const float* __restrict__ bias, float scale,
    float* __restrict__ Yf, u16* __restrict__ Yh, u16* __restrict__ Yl)
{
    __shared__ __align__(16) u16 Ash[128 * 32], Asl[128 * 32];
    __shared__ __align__(16) u16 Bsh[128 * 32];
    __shared__ __align__(16) u16 Bsl[TERMS == 3 ? 128 * 32 : 8];

    const int tid = threadIdx.x;
    const int row0 = blockIdx.x * 128, col0 = blockIdx.y * 128;
    const int w = tid >> 6, lane = tid & 63;
    const int s = lane & 15, g = lane >> 4;
    const int wrow = w >> 1, wcol = w & 1;
    const int srow = tid >> 1;
    const int skq  = (tid & 1) * 16;

    const f32x4 fz = {0.f, 0.f, 0.f, 0.f};
    f32x4 acc[4][4];
    #pragma unroll
    for (int m = 0; m < 4; ++m)
        #pragma unroll
        for (int n = 0; n < 4; ++n) acc[m][n] = fz;

    float4 aR[4];
    bf16x8 aRh[2], aRl[2], bRh[2], bRl[2];

    auto loadA = [&](int k0) {
        if (AMODE == 0) {
            const float* p = &Af32[(size_t)(row0 + srow) * kD + k0 + skq];
            aR[0] = *(const float4*)(p);
            aR[1] = *(const float4*)(p + 4);
            aR[2] = *(const float4*)(p + 8);
            aR[3] = *(const float4*)(p + 12);
        } else {
            const u16* ph = &Agh[(size_t)(row0 + srow) * kD + k0 + skq];
            const u16* pl = &Agl[(size_t)(row0 + srow) * kD + k0 + skq];
            aRh[0] = *(const bf16x8*)ph; aRh[1] = *(const bf16x8*)(ph + 8);
            aRl[0] = *(const bf16x8*)pl; aRl[1] = *(const bf16x8*)(pl + 8);
        }
    };
    auto loadB = [&](int k0) {
        const u16* ph = &Bgh[(size_t)(col0 + srow) * kD + k0 + skq];
        bRh[0] = *(const bf16x8*)ph; bRh[1] = *(const bf16x8*)(ph + 8);
        if (TERMS == 3) {
            const u16* pl = &Bgl[(size_t)(col0 + srow) * kD + k0 + skq];
            bRl[0] = *(const bf16x8*)pl; bRl[1] = *(const bf16x8*)(pl + 8);
        }
    };
    auto writeAB = [&]() {
        const int c0 = skq >> 3, sw = srow & 3;
        bf16x8 h0, h1, l0, l1;
        if (AMODE == 0) {
            const float* af = (const float*)aR;
            #pragma unroll
            for (int q = 0; q < 8; ++q) {
                u16 hh, ll;
                splitf(af[q], hh, ll);     h0[q] = (short)hh; l0[q] = (short)ll;
                splitf(af[8 + q], hh, ll); h1[q] = (short)hh; l1[q] = (short)ll;
            }
        } else { h0 = aRh[0]; h1 = aRh[1]; l0 = aRl[0]; l1 = aRl[1]; }
        *(bf16x8*)&Ash[srow * 32 + (((c0    ) ^ sw) << 3)] = h0;
        *(bf16x8*)&Ash[srow * 32 + (((c0 + 1) ^ sw) << 3)] = h1;
        *(bf16x8*)&Asl[srow * 32 + (((c0    ) ^ sw) << 3)] = l0;
        *(bf16x8*)&Asl[srow * 32 + (((c0 + 1) ^ sw) << 3)] = l1;
        *(bf16x8*)&Bsh[srow * 32 + (((c0    ) ^ sw) << 3)] = bRh[0];
        *(bf16x8*)&Bsh[srow * 32 + (((c0 + 1) ^ sw) << 3)] = bRh[1];
        if (TERMS == 3) {
            *(bf16x8*)&Bsl[srow * 32 + (((c0    ) ^ sw) << 3)] = bRl[0];
            *(bf16x8*)&Bsl[srow * 32 + (((c0 + 1) ^ sw) << 3)] = bRl[1];
        }
    };

    loadA(0); loadB(0);
    for (int k0 = 0; k0 < kD; k0 += 32) {
        __syncthreads();
        writeAB();
        __syncthreads();
        if (k0 + 32 < kD) { loadA(k0 + 32); loadB(k0 + 32); }

        bf16x8 fAh[4], fAl[4], fBh[4], fBl[4];
        #pragma unroll
        for (int m = 0; m < 4; ++m) {
            int ar = wrow * 64 + m * 16 + s;
            int off = ar * 32 + ((g ^ (ar & 3)) << 3);
            fAh[m] = *(const bf16x8*)&Ash[off];
            fAl[m] = *(const bf16x8*)&Asl[off];
        }
        #pragma unroll
        for (int n = 0; n < 4; ++n) {
            int bc = wcol * 64 + n * 16 + s;
            int off = bc * 32 + ((g ^ (bc & 3)) << 3);
            fBh[n] = *(const bf16x8*)&Bsh[off];
            if (TERMS == 3) fBl[n] = *(const bf16x8*)&Bsl[off];
        }
        #pragma unroll
        for (int m = 0; m < 4; ++m)
            #pragma unroll
            for (int n = 0; n < 4; ++n) {
                acc[m][n] = MFMA(fAh[m], fBh[n], acc[m][n]);
                acc[m][n] = MFMA(fAl[m], fBh[n], acc[m][n]);
                if (TERMS == 3) acc[m][n] = MFMA(fAh[m], fBl[n], acc[m][n]);
            }
    }

    #pragma unroll
    for (int n = 0; n < 4; ++n) {
        const int colg = col0 + wcol * 64 + n * 16 + s;
        const float bv = bias[colg];
        #pragma unroll
        for (int m = 0; m < 4; ++m) {
            const int rowg = row0 + wrow * 64 + m * 16 + (g << 2);
            #pragma unroll
            for (int r = 0; r < 4; ++r) {
                float val = (acc[m][n][r] + bv) * scale;
                if (OMODE == 1) {
                    Yf[(size_t)(rowg + r) * kD + colg] = val;
                } else {
                    const int rg = rowg + r;
                    const int b = rg >> 11, i = rg & (kL - 1);
                    const int h = colg >> 6, d = colg & 63;
                    size_t o = (((size_t)b * kH + h) * kL + i) * kDK + d;
                    if (OMODE == 0) { u16 hh, ll; splitf(val, hh, ll); Yh[o] = hh; Yl[o] = ll; }
                    else             { Yh[o] = f2bf(val); }
                }
            }
        }
    }
}

// ---------------------------------------------------------------------------
// K3a: 64x64 tile transpose  vh[bh][j][d] -> vT[bh][d][j]
// ---------------------------------------------------------------------------
__global__ __launch_bounds__(256) void transpose64(const u16* __restrict__ src,
                                                   u16* __restrict__ dst) {
    __shared__ u16 tls[64][72];
    const int tid = threadIdx.x;
    const int bh = blockIdx.y, j0 = blockIdx.x * 64;
    const int jr = tid >> 2, d0 = (tid & 3) * 16;
    const u16* p = src + ((size_t)bh * kL + j0 + jr) * kDK + d0;
    *(bf16x8*)&tls[jr][d0]     = *(const bf16x8*)p;
    *(bf16x8*)&tls[jr][d0 + 8] = *(const bf16x8*)(p + 8);
    __syncthreads();
    const int dr = tid >> 2, jc = (tid & 3) * 16;
    __align__(16) u16 tmp[16];
    #pragma unroll
    for (int q = 0; q < 16; ++q) tmp[q] = tls[jc + q][dr];
    u16* pd = dst + ((size_t)bh * kDK + dr) * kL + j0 + jc;
    *(bf16x8*)pd       = *(const bf16x8*)&tmp[0];
    *(bf16x8*)(pd + 8) = *(const bf16x8*)&tmp[8];
}

// ---------------------------------------------------------------------------
// K3: flash attention; single-bf16 Q/K/V/P, exp2 domain, STATIC softmax max
//     (shift-invariant; division by l renormalizes exactly), per-thread l
//     accumulation, Hankel-keyed bias table (b64 gather), hoisted LDS offsets.
// ---------------------------------------------------------------------------
__global__ __launch_bounds__(256, 2) void attn3(
    const u16* __restrict__ Qh,
    const u16* __restrict__ Kg, const u16* __restrict__ VT,
    const u16* __restrict__ Wr,
    u16* __restrict__ Ch, u16* __restrict__ Cl)
{
    __shared__ __align__(16) u16 Ksh[2][64 * 64];   // [j][d] swizzled
    __shared__ __align__(16) u16 Vsh[2][64 * 64];   // V^T [d][j] swizzled
    __shared__ __align__(16) u16 Wsh[2][64 * 64];   // [u_loc][d] swizzled
    __shared__ __align__(16) u16 Ps[4][16 * 64];    // per-wave P bf16, swizzled
    __shared__ __align__(16) u16 Tb[4][128 * 20];   // per-wave bias, key=(w16+j)&127, stride 20

    const int tid = threadIdx.x;
    const int w = tid >> 6, lane = tid & 63;
    const int s = lane & 15, g = lane >> 4;
    const int bh = blockIdx.y, i0 = blockIdx.x * 64;
    const int b = bh >> 4, h = bh & 15;

    const int srow = tid >> 3;      // staging: dest row (tid>>3)+32*it
    const int sc = tid & 7;         // dest 16B chunk

    auto stageK = [&](int buf, int t) {
        const u16* base = Kg + ((size_t)bh * kL + (size_t)t * 64) * kDK;
        #pragma unroll
        for (int it = 0; it < 2; ++it) {
            int r = srow + it * 32;
            gll16(base + r * 64 + ((sc ^ (r & 7)) << 3), &Ksh[buf][it * 2048 + w * 512]);
        }
    };
    auto stageV = [&](int buf, int t) {
        #pragma unroll
        for (int it = 0; it < 2; ++it) {
            int d = srow + it * 32;
            const u16* src = VT + ((size_t)bh * kDK + d) * kL + t * 64 + ((sc ^ (d & 7)) << 3);
            gll16(src, &Vsh[buf][it * 2048 + w * 512]);
        }
    };
    auto stageW = [&](int buf, int c) {
        #pragma unroll
        for (int it = 0; it < 2; ++it) {
            int r = srow + it * 32;
            long row = (long)i0 + 64L * c + r;
            if (row > kWrelMax) row = kWrelMax;
            gll16(Wr + row * 64 + ((sc ^ (r & 7)) << 3), &Wsh[buf][it * 2048 + w * 512]);
        }
    };

    // ---- hoisted LDS fragment offsets (computed once) ----
    int foff[4][2];                 // K/V/W fragment reads (same formula)
    #pragma unroll
    for (int n = 0; n < 4; ++n)
        #pragma unroll
        for (int ks = 0; ks < 2; ++ks) {
            int row = n * 16 + s;
            foff[n][ks] = row * 64 + (((ks * 4 + g) ^ (row & 7)) << 3);
        }
    int prd[2];                     // Ps fragment reads
    #pragma unroll
    for (int ks = 0; ks < 2; ++ks)
        prd[ks] = s * 64 + (((ks * 4 + g) ^ (s & 7)) << 3);
    int pwoff[4][4];                // Ps element writes
    #pragma unroll
    for (int jn = 0; jn < 4; ++jn)
        #pragma unroll
        for (int r = 0; r < 4; ++r) {
            int il = g * 4 + r, j = jn * 16 + s;
            pwoff[jn][r] = il * 64 + (((j >> 3) ^ (il & 7)) << 3) + (j & 7);
        }

    // Q fragments (pre-scaled by 0.125*log2e in projection)
    const size_t qbase = ((size_t)bh * kL + i0 + w * 16 + s) * kDK + g * 8;
    bf16x8 qh[2];
    qh[0] = *(const bf16x8*)&Qh[qbase];
    qh[1] = *(const bf16x8*)&Qh[qbase + 32];

    // T-gemm (log2-domain bias): T[il][u] stored Hankel-keyed:
    // Tb[key = (u - i0 - il) & 127][il], row stride 20 (8B-aligned b64 reads).
    auto computeT = [&](int c, int buf) {
        const f32x4 fz = {0.f, 0.f, 0.f, 0.f};
        f32x4 tacc[4] = {fz, fz, fz, fz};
        #pragma unroll
        for (int un = 0; un < 4; ++un)
            #pragma unroll
            for (int ks = 0; ks < 2; ++ks) {
                bf16x8 wf = *(const bf16x8*)&Wsh[buf][foff[un][ks]];
                tacc[un] = MFMA(qh[ks], wf, tacc[un]);
            }
        const int cb = c * 64 + s - g * 4;
        #pragma unroll
        for (int un = 0; un < 4; ++un)
            #pragma unroll
            for (int r = 0; r < 4; ++r) {
                int key = (cb + un * 16 - r) & 127;
                Tb[w][key * 20 + g * 4 + r] =
                    (u16)(__float_as_uint(tacc[un][r]) >> 16);
            }
    };

    // prologue: stage tile 0 + W chunks 0,1; then T chunks 0,1
    stageK(0, 0); stageV(0, 0); stageW(0, 0); stageW(1, 1);
    __syncthreads();
    computeT(0, 0); computeT(1, 1);
    __syncthreads();

    float lS[4] = {0.f, 0.f, 0.f, 0.f};
    const f32x4 fz = {0.f, 0.f, 0.f, 0.f};
    f32x4 oacc[4] = {fz, fz, fz, fz};

    for (int t = 0; t < 32; ++t) {
        const int cur = t & 1, nxt = cur ^ 1;
        if (t < 31) {                 // async prefetch next tile + W chunk t+2
            stageK(nxt, t + 1);
            stageV(nxt, t + 1);
            stageW(cur, t + 2);
        }
        if (t >= 1) computeT(t + 1, nxt);   // W chunk t+1 staged at t-1

        // ---- S~ = log2e/8 * (QK + bias): QK part ----
        f32x4 sacc[4] = {fz, fz, fz, fz};
        #pragma unroll
        for (int jn = 0; jn < 4; ++jn)
            #pragma unroll
            for (int ks = 0; ks < 2; ++ks) {
                bf16x8 kf = *(const bf16x8*)&Ksh[cur][foff[jn][ks]];
                sacc[jn] = MFMA(qh[ks], kf, sacc[jn]);
            }

        // ---- bias gather: one b64 per jn (4 consecutive il entries) ----
        #pragma unroll
        for (int jn = 0; jn < 4; ++jn) {
            int key = (w * 16 + t * 64 + jn * 16 + s) & 127;
            ushort4 tv = *(const ushort4*)&Tb[w][key * 20 + g * 4];
            sacc[jn][0] += bf2f(tv.x);
            sacc[jn][1] += bf2f(tv.y);
            sacc[jn][2] += bf2f(tv.z);
            sacc[jn][3] += bf2f(tv.w);
        }

        // ---- p = exp2(s - M), truncate to bf16; per-thread l accumulation ----
        #pragma unroll
        for (int jn = 0; jn < 4; ++jn)
            #pragma unroll
            for (int r = 0; r < 4; ++r) {
                float p = fexp2(sacc[jn][r] - kM);
                u32 pu = __float_as_uint(p) & 0xFFFF0000u;
                lS[r] += __uint_as_float(pu);
                Ps[w][pwoff[jn][r]] = (u16)(pu >> 16);
            }

        // ---- O += P V ----
        #pragma unroll
        for (int ks = 0; ks < 2; ++ks) {
            bf16x8 pf = *(const bf16x8*)&Ps[w][prd[ks]];
            #pragma unroll
            for (int dn = 0; dn < 4; ++dn) {
                bf16x8 vf = *(const bf16x8*)&Vsh[cur][foff[dn][ks]];
                oacc[dn] = MFMA(pf, vf, oacc[dn]);
            }
        }
        __syncthreads();   // drains gll (vmcnt) + releases cur buffers
    }

    // ---- epilogue: reduce l across the 16 s-lanes, then O/l ----
    float inv[4];
    #pragma unroll
    for (int r = 0; r < 4; ++r) {
        float ps = lS[r];
        ps += __shfl_xor(ps, 1);
        ps += __shfl_xor(ps, 2);
        ps += __shfl_xor(ps, 4);
        ps += __shfl_xor(ps, 8);
        inv[r] = 1.0f / ps;
    }
    #pragma unroll
    for (int dn = 0; dn < 4; ++dn)
        #pragma unroll
        for (int r = 0; r < 4; ++r) {
            const int ig = i0 + w * 16 + g * 4 + r;
            float val = oacc[dn][r] * inv[r];
            u16 hh, ll; splitf(val, hh, ll);
            size_t o = ((size_t)(b * kL + ig)) * kD + h * kDK + dn * 16 + s;
            Ch[o] = hh; Cl[o] = ll;
        }
}

// ---------------------------------------------------------------------------
extern "C" void kernel_launch(void* const* d_in, const int* in_sizes, int n_in,
                              void* d_out, int out_size, void* d_ws, size_t ws_size,
                              hipStream_t stream) {
    const float* q    = (const float*)d_in[0];
    const float* k    = (const float*)d_in[1];
    const float* v    = (const float*)d_in[2];
    const float* Wq   = (const float*)d_in[3];
    const float* bq   = (const float*)d_in[4];
    const float* Wk   = (const float*)d_in[5];
    const float* bk   = (const float*)d_in[6];
    const float* Wv   = (const float*)d_in[7];
    const float* bv   = (const float*)d_in[8];
    const float* Wo   = (const float*)d_in[9];
    const float* bo   = (const float*)d_in[10];
    const float* wrel = (const float*)d_in[11];
    float* out = (float*)d_out;

    u16* p = (u16*)d_ws;
    const size_t nW = (size_t)kD * kD;
    const size_t nR = (size_t)(2 * kL - 1) * kDK;
    const size_t nT = (size_t)kB * kL * kD;
    u16* wqh = p; p += nW;  u16* wql = p; p += nW;
    u16* wkh = p; p += nW;  u16* wkl = p; p += nW;
    u16* wvh = p; p += nW;  u16* wvl = p; p += nW;
    u16* woh = p; p += nW;  u16* wol = p; p += nW;
    u16* wrh = p; p += nR;  u16* wrl = p; p += nR;
    u16* qhh = p; p += nT;
    u16* khh = p; p += nT;
    u16* vhh = p; p += nT;
    u16* vT  = p; p += nT;
    u16* cch = p; p += nT;  u16* ccl = p; p += nT;

    hipLaunchKernelGGL(split4_kernel, dim3(1024), dim3(256), 0, stream, Wq, wqh, wql, (int)(nW / 4));
    hipLaunchKernelGGL(split4_kernel, dim3(1024), dim3(256), 0, stream, Wk, wkh, wkl, (int)(nW / 4));
    hipLaunchKernelGGL(split4_kernel, dim3(1024), dim3(256), 0, stream, Wv, wvh, wvl, (int)(nW / 4));
    hipLaunchKernelGGL(split4_kernel, dim3(1024), dim3(256), 0, stream, Wo, woh, wol, (int)(nW / 4));
    hipLaunchKernelGGL(split4_kernel, dim3(256),  dim3(256), 0, stream, wrel, wrh, wrl, (int)(nR / 4));

    dim3 blk(256);
    dim3 gP(kR / 128, kD / 128);
    // Q pre-scaled by (1/sqrt(dk))*log2(e); all head outputs single-bf16.
    hipLaunchKernelGGL((mfma_gemm<0, 2, 2>), gP, blk, 0, stream,
                       q, nullptr, nullptr, wqh, wql, bq, kQScale, nullptr, qhh, nullptr);
    hipLaunchKernelGGL((mfma_gemm<0, 2, 2>), gP, blk, 0, stream,
                       k, nullptr, nullptr, wkh, wkl, bk, 1.0f, nullptr, khh, nullptr);
    hipLaunchKernelGGL((mfma_gemm<0, 2, 2>), gP, blk, 0, stream,
                       v, nullptr, nullptr, wvh, wvl, bv, 1.0f, nullptr, vhh, nullptr);

    hipLaunchKernelGGL(transpose64, dim3(kL / 64, kB * kH), blk, 0, stream, vhh, vT);

    hipLaunchKernelGGL(attn3, dim3(kL / 64, kB * kH), blk, 0, stream,
                       qhh, khh, vT, wrh, cch, ccl);

    hipLaunchKernelGGL((mfma_gemm<1, 1, 3>), gP, blk, 0, stream,
                       nullptr, cch, ccl, woh, wol, bo, 1.0f, out, nullptr, nullptr);
}

// Round 7
// 409.764 us; speedup vs baseline: 8.5335x; 1.0965x over previous
//
#include <hip/hip_runtime.h>

typedef __attribute__((ext_vector_type(8))) short bf16x8;
typedef __attribute__((ext_vector_type(4))) float f32x4;
typedef unsigned short u16;
typedef unsigned int u32;

constexpr int kB = 4, kL = 2048, kD = 1024, kH = 16, kDK = 64;
constexpr int kR = kB * kL;
constexpr long kWrelMax = 2 * kL - 2;   // 4094 = last valid w_rel row
constexpr float kQScale = 0.125f * 1.44269504088896f;  // 1/sqrt(dk) * log2(e)
constexpr float kM = 12.0f;             // static softmax shift (log2 domain)

__device__ inline float fexp2(float x) { return __builtin_amdgcn_exp2f(x); }

__device__ inline u16 f2bf(float x) {
    union { float f; u32 u; } v; v.f = x;
    u32 r = v.u + 0x7FFFu + ((v.u >> 16) & 1u);   // RNE
    return (u16)(r >> 16);
}
__device__ inline float bf2f(u16 h) {
    union { u32 u; float f; } v; v.u = ((u32)h) << 16;
    return v.f;
}
// trunc split: hi = trunc_bf16(x), lo = trunc_bf16(x - hi). Residual error
// ~2^-16 relative — absorbed by the 2/3-term GEMM error budget. 4 VALU ops.
__device__ inline void splitf(float x, u16& hi, u16& lo) {
    union { float f; u32 u; } v; v.f = x;
    u32 hu = v.u & 0xFFFF0000u;
    hi = (u16)(hu >> 16);
    union { u32 u; float f; } hf; hf.u = hu;
    union { float f; u32 u; } l; l.f = x - hf.f;
    lo = (u16)(l.u >> 16);
}
__device__ inline f32x4 MFMA(bf16x8 a, bf16x8 b, f32x4 c) {
    return __builtin_amdgcn_mfma_f32_16x16x32_bf16(a, b, c, 0, 0, 0);
}
// async global->LDS, 16B per lane; LDS dest = wave-uniform base + lane*16
__device__ __forceinline__ void gll16(const u16* g, u16* l) {
    __builtin_amdgcn_global_load_lds(
        (const __attribute__((address_space(1))) u32*)g,
        (__attribute__((address_space(3))) u32*)l, 16, 0, 0);
}

// ---------------------------------------------------------------------------
// K1: fp32 -> bf16 hi/lo split; 4 tensors in one launch (blockIdx.y selects)
// ---------------------------------------------------------------------------
__global__ void split4x4_kernel(const float* __restrict__ i0, const float* __restrict__ i1,
                                const float* __restrict__ i2, const float* __restrict__ i3,
                                u16* __restrict__ h0, u16* __restrict__ h1,
                                u16* __restrict__ h2, u16* __restrict__ h3,
                                u16* __restrict__ l0, u16* __restrict__ l1,
                                u16* __restrict__ l2, u16* __restrict__ l3, int n4) {
    int idx = blockIdx.x * blockDim.x + threadIdx.x;
    if (idx >= n4) return;
    const float* in = blockIdx.y == 0 ? i0 : blockIdx.y == 1 ? i1 : blockIdx.y == 2 ? i2 : i3;
    u16* hi = blockIdx.y == 0 ? h0 : blockIdx.y == 1 ? h1 : blockIdx.y == 2 ? h2 : h3;
    u16* lo = blockIdx.y == 0 ? l0 : blockIdx.y == 1 ? l1 : blockIdx.y == 2 ? l2 : l3;
    float4 x = reinterpret_cast<const float4*>(in)[idx];
    ushort4 h, l;
    splitf(x.x, h.x, l.x); splitf(x.y, h.y, l.y);
    splitf(x.z, h.z, l.z); splitf(x.w, h.w, l.w);
    reinterpret_cast<ushort4*>(hi)[idx] = h;
    reinterpret_cast<ushort4*>(lo)[idx] = l;
}
__global__ void split4_kernel(const float* __restrict__ in,
                              u16* __restrict__ hi, u16* __restrict__ lo, int n4) {
    int idx = blockIdx.x * blockDim.x + threadIdx.x;
    if (idx >= n4) return;
    float4 x = reinterpret_cast<const float4*>(in)[idx];
    ushort4 h, l;
    splitf(x.x, h.x, l.x); splitf(x.y, h.y, l.y);
    splitf(x.z, h.z, l.z); splitf(x.w, h.w, l.w);
    reinterpret_cast<ushort4*>(hi)[idx] = h;
    reinterpret_cast<ushort4*>(lo)[idx] = l;
}

// ---------------------------------------------------------------------------
// K2/K4: MFMA GEMM  Y = (X @ W^T + bias) * scale
//  AMODE 0: A fp32 global, split on the fly.  AMODE 1: A pre-split bf16.
//  OMODE 1: fp32 plain.  OMODE 2: head layout, bf16 hi only.
//  OMODE 3: transposed head layout vT[bh][d][i], bf16 hi only (V path).
//  TERMS 2: Ah*Bh + Al*Bh (exact-A x bf16-B).  TERMS 3: + Ah*Bl.
// ---------------------------------------------------------------------------
template<int AMODE, int OMODE, int TERMS>
__global__ __launch_bounds__(256) void mfma_gemm(
    const float* __restrict__ Af32,
    const u16* __restrict__ Agh, const u16* __restrict__ Agl,
    const u16* __restrict__ Bgh, const u16* __restrict__ Bgl,
    const float* __restrict__ bias, float scale,
    float* __restrict__ Yf, u16* __restrict__ Yh, u16* __restrict__ Yl)
{
    __shared__ __align__(16) u16 Ash[128 * 32], Asl[128 * 32];
    __shared__ __align__(16) u16 Bsh[128 * 32];
    __shared__ __align__(16) u16 Bsl[TERMS == 3 ? 128 * 32 : 8];

    const int tid = threadIdx.x;
    const int row0 = blockIdx.x * 128, col0 = blockIdx.y * 128;
    const int w = tid >> 6, lane = tid & 63;
    const int s = lane & 15, g = lane >> 4;
    const int wrow = w >> 1, wcol = w & 1;
    const int srow = tid >> 1;
    const int skq  = (tid & 1) * 16;

    const f32x4 fz = {0.f, 0.f, 0.f, 0.f};
    f32x4 acc[4][4];
    #pragma unroll
    for (int m = 0; m < 4; ++m)
        #pragma unroll
        for (int n = 0; n < 4; ++n) acc[m][n] = fz;

    float4 aR[4];
    bf16x8 aRh[2], aRl[2], bRh[2], bRl[2];

    auto loadA = [&](int k0) {
        if (AMODE == 0) {
            const float* p = &Af32[(size_t)(row0 + srow) * kD + k0 + skq];
            aR[0] = *(const float4*)(p);
            aR[1] = *(const float4*)(p + 4);
            aR[2] = *(const float4*)(p + 8);
            aR[3] = *(const float4*)(p + 12);
        } else {
            const u16* ph = &Agh[(size_t)(row0 + srow) * kD + k0 + skq];
            const u16* pl = &Agl[(size_t)(row0 + srow) * kD + k0 + skq];
            aRh[0] = *(const bf16x8*)ph; aRh[1] = *(const bf16x8*)(ph + 8);
            aRl[0] = *(const bf16x8*)pl; aRl[1] = *(const bf16x8*)(pl + 8);
        }
    };
    auto loadB = [&](int k0) {
        const u16* ph = &Bgh[(size_t)(col0 + srow) * kD + k0 + skq];
        bRh[0] = *(const bf16x8*)ph; bRh[1] = *(const bf16x8*)(ph + 8);
        if (TERMS == 3) {
            const u16* pl = &Bgl[(size_t)(col0 + srow) * kD + k0 + skq];
            bRl[0] = *(const bf16x8*)pl; bRl[1] = *(const bf16x8*)(pl + 8);
        }
    };
    auto writeAB = [&]() {
        const int c0 = skq >> 3, sw = srow & 3;
        bf16x8 h0, h1, l0, l1;
        if (AMODE == 0) {
            const float* af = (const float*)aR;
            #pragma unroll
            for (int q = 0; q < 8; ++q) {
                u16 hh, ll;
                splitf(af[q], hh, ll);     h0[q] = (short)hh; l0[q] = (short)ll;
                splitf(af[8 + q], hh, ll); h1[q] = (short)hh; l1[q] = (short)ll;
            }
        } else { h0 = aRh[0]; h1 = aRh[1]; l0 = aRl[0]; l1 = aRl[1]; }
        *(bf16x8*)&Ash[srow * 32 + (((c0    ) ^ sw) << 3)] = h0;
        *(bf16x8*)&Ash[srow * 32 + (((c0 + 1) ^ sw) << 3)] = h1;
        *(bf16x8*)&Asl[srow * 32 + (((c0    ) ^ sw) << 3)] = l0;
        *(bf16x8*)&Asl[srow * 32 + (((c0 + 1) ^ sw) << 3)] = l1;
        *(bf16x8*)&Bsh[srow * 32 + (((c0    ) ^ sw) << 3)] = bRh[0];
        *(bf16x8*)&Bsh[srow * 32 + (((c0 + 1) ^ sw) << 3)] = bRh[1];
        if (TERMS == 3) {
            *(bf16x8*)&Bsl[srow * 32 + (((c0    ) ^ sw) << 3)] = bRl[0];
            *(bf16x8*)&Bsl[srow * 32 + (((c0 + 1) ^ sw) << 3)] = bRl[1];
        }
    };

    loadA(0); loadB(0);
    for (int k0 = 0; k0 < kD; k0 += 32) {
        __syncthreads();
        writeAB();
        __syncthreads();
        if (k0 + 32 < kD) { loadA(k0 + 32); loadB(k0 + 32); }

        bf16x8 fAh[4], fAl[4], fBh[4], fBl[4];
        #pragma unroll
        for (int m = 0; m < 4; ++m) {
            int ar = wrow * 64 + m * 16 + s;
            int off = ar * 32 + ((g ^ (ar & 3)) << 3);
            fAh[m] = *(const bf16x8*)&Ash[off];
            fAl[m] = *(const bf16x8*)&Asl[off];
        }
        #pragma unroll
        for (int n = 0; n < 4; ++n) {
            int bc = wcol * 64 + n * 16 + s;
            int off = bc * 32 + ((g ^ (bc & 3)) << 3);
            fBh[n] = *(const bf16x8*)&Bsh[off];
            if (TERMS == 3) fBl[n] = *(const bf16x8*)&Bsl[off];
        }
        #pragma unroll
        for (int m = 0; m < 4; ++m)
            #pragma unroll
            for (int n = 0; n < 4; ++n) {
                acc[m][n] = MFMA(fAh[m], fBh[n], acc[m][n]);
                acc[m][n] = MFMA(fAl[m], fBh[n], acc[m][n]);
                if (TERMS == 3) acc[m][n] = MFMA(fAh[m], fBl[n], acc[m][n]);
            }
    }

    #pragma unroll
    for (int n = 0; n < 4; ++n) {
        const int colg = col0 + wcol * 64 + n * 16 + s;
        const float bv = bias[colg];
        #pragma unroll
        for (int m = 0; m < 4; ++m) {
            const int rowg = row0 + wrow * 64 + m * 16 + (g << 2);
            if (OMODE == 3) {
                // vT[bh][d][i]: 4 consecutive i per thread -> ushort4 store
                const int b = rowg >> 11, i = rowg & (kL - 1);
                const int h = colg >> 6, d = colg & 63;
                ushort4 o4;
                o4.x = f2bf(acc[m][n][0] + bv);
                o4.y = f2bf(acc[m][n][1] + bv);
                o4.z = f2bf(acc[m][n][2] + bv);
                o4.w = f2bf(acc[m][n][3] + bv);
                *(ushort4*)&Yh[(((size_t)b * kH + h) * kDK + d) * kL + i] = o4;
            } else {
                #pragma unroll
                for (int r = 0; r < 4; ++r) {
                    float val = (acc[m][n][r] + bv) * scale;
                    if (OMODE == 1) {
                        Yf[(size_t)(rowg + r) * kD + colg] = val;
                    } else {
                        const int rg = rowg + r;
                        const int b = rg >> 11, i = rg & (kL - 1);
                        const int h = colg >> 6, d = colg & 63;
                        size_t o = (((size_t)b * kH + h) * kL + i) * kDK + d;
                        Yh[o] = f2bf(val);
                    }
                }
            }
        }
    }
}

// ---------------------------------------------------------------------------
// K3: flash attention; single-bf16 Q/K/V/P, exp2 domain, STATIC softmax max
//     (shift-invariant; division by l renormalizes exactly), per-thread l
//     accumulation, Hankel-keyed bias table (b64 gather), hoisted LDS offsets.
// ---------------------------------------------------------------------------
__global__ __launch_bounds__(256, 2) void attn3(
    const u16* __restrict__ Qh,
    const u16* __restrict__ Kg, const u16* __restrict__ VT,
    const u16* __restrict__ Wr,
    u16* __restrict__ Ch, u16* __restrict__ Cl)
{
    __shared__ __align__(16) u16 Ksh[2][64 * 64];   // [j][d] swizzled
    __shared__ __align__(16) u16 Vsh[2][64 * 64];   // V^T [d][j] swizzled
    __shared__ __align__(16) u16 Wsh[2][64 * 64];   // [u_loc][d] swizzled
    __shared__ __align__(16) u16 Ps[4][16 * 64];    // per-wave P bf16, swizzled
    __shared__ __align__(16) u16 Tb[4][128 * 20];   // per-wave bias, key=(w16+j)&127, stride 20

    const int tid = threadIdx.x;
    const int w = tid >> 6, lane = tid & 63;
    const int s = lane & 15, g = lane >> 4;
    const int bh = blockIdx.y, i0 = blockIdx.x * 64;
    const int b = bh >> 4, h = bh & 15;

    const int srow = tid >> 3;      // staging: dest row (tid>>3)+32*it
    const int sc = tid & 7;         // dest 16B chunk

    auto stageK = [&](int buf, int t) {
        const u16* base = Kg + ((size_t)bh * kL + (size_t)t * 64) * kDK;
        #pragma unroll
        for (int it = 0; it < 2; ++it) {
            int r = srow + it * 32;
            gll16(base + r * 64 + ((sc ^ (r & 7)) << 3), &Ksh[buf][it * 2048 + w * 512]);
        }
    };
    auto stageV = [&](int buf, int t) {
        #pragma unroll
        for (int it = 0; it < 2; ++it) {
            int d = srow + it * 32;
            const u16* src = VT + ((size_t)bh * kDK + d) * kL + t * 64 + ((sc ^ (d & 7)) << 3);
            gll16(src, &Vsh[buf][it * 2048 + w * 512]);
        }
    };
    auto stageW = [&](int buf, int c) {
        #pragma unroll
        for (int it = 0; it < 2; ++it) {
            int r = srow + it * 32;
            long row = (long)i0 + 64L * c + r;
            if (row > kWrelMax) row = kWrelMax;
            gll16(Wr + row * 64 + ((sc ^ (r & 7)) << 3), &Wsh[buf][it * 2048 + w * 512]);
        }
    };

    // ---- hoisted LDS fragment offsets (computed once) ----
    int foff[4][2];                 // K/V/W fragment reads (same formula)
    #pragma unroll
    for (int n = 0; n < 4; ++n)
        #pragma unroll
        for (int ks = 0; ks < 2; ++ks) {
            int row = n * 16 + s;
            foff[n][ks] = row * 64 + (((ks * 4 + g) ^ (row & 7)) << 3);
        }
    int prd[2];                     // Ps fragment reads
    #pragma unroll
    for (int ks = 0; ks < 2; ++ks)
        prd[ks] = s * 64 + (((ks * 4 + g) ^ (s & 7)) << 3);
    int pwoff[4][4];                // Ps element writes
    #pragma unroll
    for (int jn = 0; jn < 4; ++jn)
        #pragma unroll
        for (int r = 0; r < 4; ++r) {
            int il = g * 4 + r, j = jn * 16 + s;
            pwoff[jn][r] = il * 64 + (((j >> 3) ^ (il & 7)) << 3) + (j & 7);
        }

    // Q fragments (pre-scaled by 0.125*log2e in projection)
    const size_t qbase = ((size_t)bh * kL + i0 + w * 16 + s) * kDK + g * 8;
    bf16x8 qh[2];
    qh[0] = *(const bf16x8*)&Qh[qbase];
    qh[1] = *(const bf16x8*)&Qh[qbase + 32];

    // T-gemm (log2-domain bias): T[il][u] stored Hankel-keyed:
    // Tb[key = (u - i0 - il) & 127][il], row stride 20 (8B-aligned b64 reads).
    auto computeT = [&](int c, int buf) {
        const f32x4 fz = {0.f, 0.f, 0.f, 0.f};
        f32x4 tacc[4] = {fz, fz, fz, fz};
        #pragma unroll
        for (int un = 0; un < 4; ++un)
            #pragma unroll
            for (int ks = 0; ks < 2; ++ks) {
                bf16x8 wf = *(const bf16x8*)&Wsh[buf][foff[un][ks]];
                tacc[un] = MFMA(qh[ks], wf, tacc[un]);
            }
        const int cb = c * 64 + s - g * 4;
        #pragma unroll
        for (int un = 0; un < 4; ++un)
            #pragma unroll
            for (int r = 0; r < 4; ++r) {
                int key = (cb + un * 16 - r) & 127;
                Tb[w][key * 20 + g * 4 + r] =
                    (u16)(__float_as_uint(tacc[un][r]) >> 16);
            }
    };

    // prologue: stage tile 0 + W chunks 0,1; then T chunks 0,1
    stageK(0, 0); stageV(0, 0); stageW(0, 0); stageW(1, 1);
    __syncthreads();
    computeT(0, 0); computeT(1, 1);
    __syncthreads();

    float lS[4] = {0.f, 0.f, 0.f, 0.f};
    const f32x4 fz = {0.f, 0.f, 0.f, 0.f};
    f32x4 oacc[4] = {fz, fz, fz, fz};

    for (int t = 0; t < 32; ++t) {
        const int cur = t & 1, nxt = cur ^ 1;
        if (t < 31) {                 // async prefetch next tile + W chunk t+2
            stageK(nxt, t + 1);
            stageV(nxt, t + 1);
            stageW(cur, t + 2);
        }
        if (t >= 1) computeT(t + 1, nxt);   // W chunk t+1 staged at t-1

        // ---- S~ = log2e/8 * (QK + bias): QK part ----
        f32x4 sacc[4] = {fz, fz, fz, fz};
        __builtin_amdgcn_s_setprio(1);
        #pragma unroll
        for (int jn = 0; jn < 4; ++jn)
            #pragma unroll
            for (int ks = 0; ks < 2; ++ks) {
                bf16x8 kf = *(const bf16x8*)&Ksh[cur][foff[jn][ks]];
                sacc[jn] = MFMA(qh[ks], kf, sacc[jn]);
            }
        __builtin_amdgcn_s_setprio(0);

        // ---- bias gather: one b64 per jn (4 consecutive il entries) ----
        #pragma unroll
        for (int jn = 0; jn < 4; ++jn) {
            int key = (w * 16 + t * 64 + jn * 16 + s) & 127;
            ushort4 tv = *(const ushort4*)&Tb[w][key * 20 + g * 4];
            sacc[jn][0] += bf2f(tv.x);
            sacc[jn][1] += bf2f(tv.y);
            sacc[jn][2] += bf2f(tv.z);
            sacc[jn][3] += bf2f(tv.w);
        }

        // ---- p = exp2(s - M), truncate to bf16; per-thread l accumulation ----
        #pragma unroll
        for (int jn = 0; jn < 4; ++jn)
            #pragma unroll
            for (int r = 0; r < 4; ++r) {
                float p = fexp2(sacc[jn][r] - kM);
                u32 pu = __float_as_uint(p) & 0xFFFF0000u;
                lS[r] += __uint_as_float(pu);
                Ps[w][pwoff[jn][r]] = (u16)(pu >> 16);
            }

        // ---- O += P V ----
        __builtin_amdgcn_s_setprio(1);
        #pragma unroll
        for (int ks = 0; ks < 2; ++ks) {
            bf16x8 pf = *(const bf16x8*)&Ps[w][prd[ks]];
            #pragma unroll
            for (int dn = 0; dn < 4; ++dn) {
                bf16x8 vf = *(const bf16x8*)&Vsh[cur][foff[dn][ks]];
                oacc[dn] = MFMA(pf, vf, oacc[dn]);
            }
        }
        __builtin_amdgcn_s_setprio(0);
        __syncthreads();   // drains gll (vmcnt) + releases cur buffers
    }

    // ---- epilogue: reduce l across the 16 s-lanes, then O/l ----
    float inv[4];
    #pragma unroll
    for (int r = 0; r < 4; ++r) {
        float ps = lS[r];
        ps += __shfl_xor(ps, 1);
        ps += __shfl_xor(ps, 2);
        ps += __shfl_xor(ps, 4);
        ps += __shfl_xor(ps, 8);
        inv[r] = 1.0f / ps;
    }
    #pragma unroll
    for (int dn = 0; dn < 4; ++dn)
        #pragma unroll
        for (int r = 0; r < 4; ++r) {
            const int ig = i0 + w * 16 + g * 4 + r;
            float val = oacc[dn][r] * inv[r];
            u16 hh, ll; splitf(val, hh, ll);
            size_t o = ((size_t)(b * kL + ig)) * kD + h * kDK + dn * 16 + s;
            Ch[o] = hh; Cl[o] = ll;
        }
}

// ---------------------------------------------------------------------------
extern "C" void kernel_launch(void* const* d_in, const int* in_sizes, int n_in,
                              void* d_out, int out_size, void* d_ws, size_t ws_size,
                              hipStream_t stream) {
    const float* q    = (const float*)d_in[0];
    const float* k    = (const float*)d_in[1];
    const float* v    = (const float*)d_in[2];
    const float* Wq   = (const float*)d_in[3];
    const float* bq   = (const float*)d_in[4];
    const float* Wk   = (const float*)d_in[5];
    const float* bk   = (const float*)d_in[6];
    const float* Wv   = (const float*)d_in[7];
    const float* bv   = (const float*)d_in[8];
    const float* Wo   = (const float*)d_in[9];
    const float* bo   = (const float*)d_in[10];
    const float* wrel = (const float*)d_in[11];
    float* out = (float*)d_out;

    u16* p = (u16*)d_ws;
    const size_t nW = (size_t)kD * kD;
    const size_t nR = (size_t)(2 * kL - 1) * kDK;
    const size_t nT = (size_t)kB * kL * kD;
    u16* wqh = p; p += nW;  u16* wql = p; p += nW;
    u16* wkh = p; p += nW;  u16* wkl = p; p += nW;
    u16* wvh = p; p += nW;  u16* wvl = p; p += nW;
    u16* woh = p; p += nW;  u16* wol = p; p += nW;
    u16* wrh = p; p += nR;  u16* wrl = p; p += nR;
    u16* qhh = p; p += nT;
    u16* khh = p; p += nT;
    u16* vT  = p; p += nT;
    u16* cch = p; p += nT;  u16* ccl = p; p += nT;

    // K1: weight splits (4 fused) + w_rel split
    hipLaunchKernelGGL(split4x4_kernel, dim3(1024, 4), dim3(256), 0, stream,
                       Wq, Wk, Wv, Wo, wqh, wkh, wvh, woh, wql, wkl, wvl, wol,
                       (int)(nW / 4));
    hipLaunchKernelGGL(split4_kernel, dim3(256), dim3(256), 0, stream,
                       wrel, wrh, wrl, (int)(nR / 4));

    dim3 blk(256);
    dim3 gP(kR / 128, kD / 128);
    // Q pre-scaled by (1/sqrt(dk))*log2(e); K head layout; V transposed direct.
    hipLaunchKernelGGL((mfma_gemm<0, 2, 2>), gP, blk, 0, stream,
                       q, nullptr, nullptr, wqh, wql, bq, kQScale, nullptr, qhh, nullptr);
    hipLaunchKernelGGL((mfma_gemm<0, 2, 2>), gP, blk, 0, stream,
                       k, nullptr, nullptr, wkh, wkl, bk, 1.0f, nullptr, khh, nullptr);
    hipLaunchKernelGGL((mfma_gemm<0, 3, 2>), gP, blk, 0, stream,
                       v, nullptr, nullptr, wvh, wvl, bv, 1.0f, nullptr, vT, nullptr);

    hipLaunchKernelGGL(attn3, dim3(kL / 64, kB * kH), blk, 0, stream,
                       qhh, khh, vT, wrh, cch, ccl);

    hipLaunchKernelGGL((mfma_gemm<1, 1, 3>), gP, blk, 0, stream,
                       nullptr, cch, ccl, woh, wol, bo, 1.0f, out, nullptr, nullptr);
}